// Round 9
// baseline (896.119 us; speedup 1.0000x reference)
//
#include <hip/hip_runtime.h>
#include <hip/hip_bf16.h>
#include <math.h>

#define NPTS 2048
#define NCLOUD 32
#define NTOT (NPTS*NCLOUD)
#define CIN 64
#define COUT 128
#define KNN 16
#define KSUB 16            // kept per subset (16 = structural superset guarantee)
#define NCAND 128          // 8 subsets (2 col-halves x 4 quads) * 16

typedef __attribute__((ext_vector_type(8))) short short8v;   // 8 bf16 (4 VGPR)
typedef __attribute__((ext_vector_type(4))) float float4v;   // 4 fp32

__device__ __forceinline__ unsigned short f2bf(float f) {    // RNE float->bf16
    unsigned u = __float_as_uint(f);
    return (unsigned short)((u + 0x7fffu + ((u >> 16) & 1u)) >> 16);
}

// ---------------- K0: bf16 hi plane + |q|^2 (fp32, ranking-only) ----------------
__global__ void k0_prep(const float* __restrict__ x, unsigned short* __restrict__ xhi,
                        float* __restrict__ sq)
{
    const int p = blockIdx.x * 256 + threadIdx.x;
    const float* src = x + (size_t)p * CIN;
    float s = 0.f;
    #pragma unroll
    for (int i = 0; i < 8; ++i) {
        float4 v0 = *reinterpret_cast<const float4*>(src + 8*i);
        float4 v1 = *reinterpret_cast<const float4*>(src + 8*i + 4);
        float e[8] = {v0.x,v0.y,v0.z,v0.w,v1.x,v1.y,v1.z,v1.w};
        short8v h;
        #pragma unroll
        for (int u = 0; u < 8; ++u) {
            h[u] = (short)f2bf(e[u]);
            s = fmaf(e[u], e[u], s);
        }
        *reinterpret_cast<short8v*>(xhi + (size_t)p*CIN + 8*i) = h;
    }
    sq[p] = s;
}

// ---------------- K1: MFMA swapped-operand KNN + batched bitonic top-16 ----------------
// 2048 blocks: wid = xcd-swizzled work id; rowgroup = wid>>1 (64 rows), half = wid&1
// (columns half*1024 .. +1023). Wave owns 16 rows (j=lane&15); quad covers cols
// {quad*4+r + 16*t}. 8 subsets x top-16 -> structural superset of true top-16.
// hi-only bf16 ranking (err ~0.05 << subset tolerance); exact rerank in k2.
__global__ __launch_bounds__(256,1) void k1_knn(const unsigned short* __restrict__ xhi,
                                                const float* __restrict__ sq,
                                                unsigned short* __restrict__ cand)
{
    const int wid  = ((blockIdx.x & 7) << 8) + (blockIdx.x >> 3);  // XCD swizzle (4 clouds/XCD)
    const int o    = wid >> 1;           // row group (64 rows)
    const int half = wid & 1;            // column half
    const int wave = threadIdx.x >> 6;
    const int lane = threadIdx.x & 63;
    const int j    = lane & 15;
    const int quad = lane >> 4;
    const int rowglob = o*64 + wave*16 + j;
    const int cbase   = (rowglob >> 11) << 11;     // cloud base point id

    short8v bhi[2];
    #pragma unroll
    for (int kk = 0; kk < 2; ++kk)
        bhi[kk] = *reinterpret_cast<const short8v*>(xhi + (size_t)rowglob*CIN + quad*8 + kk*32);

    unsigned kd[KSUB];                 // sorted DESC: kd[0] = worst kept
    #pragma unroll
    for (int k = 0; k < KSUB; ++k) kd[k] = 0xFFFFFFFFu;

    for (int it4 = 0; it4 < 16; ++it4) {           // 16 outer iters x 64 cols
        unsigned key[16];
        #pragma unroll
        for (int sub = 0; sub < 4; ++sub) {
            const int colb = half*1024 + it4*64 + sub*16;
            const size_t abase = (size_t)(cbase + colb + j)*CIN + quad*8;
            const short8v ahi0 = *reinterpret_cast<const short8v*>(xhi + abase);
            const short8v ahi1 = *reinterpret_cast<const short8v*>(xhi + abase + 32);

            float4v acc0 = {0.f,0.f,0.f,0.f}, acc1 = {0.f,0.f,0.f,0.f};
            acc0 = __builtin_amdgcn_mfma_f32_16x16x32_bf16(ahi0, bhi[0], acc0, 0,0,0);
            acc1 = __builtin_amdgcn_mfma_f32_16x16x32_bf16(ahi1, bhi[1], acc1, 0,0,0);

            const float4v sqv = *reinterpret_cast<const float4v*>(sq + cbase + colb + quad*4);
            const unsigned idxbase = (unsigned)(colb + quad*4);
            #pragma unroll
            for (int r = 0; r < 4; ++r) {
                const float s = fmaf(-2.f, acc0[r] + acc1[r], sqv[r]);
                unsigned u = __float_as_uint(s);
                u ^= (unsigned)(((int)u >> 31) | 0x80000000);   // monotone float->uint
                key[sub*4 + r] = (u & 0xFFFFF800u) | (idxbase + r);
            }
        }

        // bitonic sort key[16] ascending (static indices, full ILP)
        #pragma unroll
        for (int k = 2; k <= 16; k <<= 1) {
            #pragma unroll
            for (int jj = k >> 1; jj > 0; jj >>= 1) {
                #pragma unroll
                for (int i = 0; i < 16; ++i) {
                    const int l = i ^ jj;
                    if (l > i) {
                        const bool asc = ((i & k) == 0);
                        const unsigned a = key[i], b = key[l];
                        const unsigned mn = min(a, b), mx = max(a, b);
                        key[i] = asc ? mn : mx;
                        key[l] = asc ? mx : mn;
                    }
                }
            }
        }
        // half-cleaner: [kd desc | key asc] -> low half = exact bottom-16 of union
        #pragma unroll
        for (int i = 0; i < 16; ++i) kd[i] = min(kd[i], key[i]);
        // bitonic-merge kd back to desc
        #pragma unroll
        for (int jj = 8; jj > 0; jj >>= 1) {
            #pragma unroll
            for (int i = 0; i < 16; ++i) {
                const int l = i ^ jj;
                if (l > i) {
                    const unsigned a = kd[i], b = kd[l];
                    kd[i] = max(a, b); kd[l] = min(a, b);
                }
            }
        }
    }
    // store 16 u16 cloud-local ids (32B per lane)
    unsigned short* dst = cand + (size_t)rowglob*NCAND + half*64 + quad*KSUB;
    #pragma unroll
    for (int k = 0; k < 2; ++k) {
        int4 w;
        w.x = (int)((kd[8*k+0] & 0x7FFu) | ((kd[8*k+1] & 0x7FFu) << 16));
        w.y = (int)((kd[8*k+2] & 0x7FFu) | ((kd[8*k+3] & 0x7FFu) << 16));
        w.z = (int)((kd[8*k+4] & 0x7FFu) | ((kd[8*k+5] & 0x7FFu) << 16));
        w.w = (int)((kd[8*k+6] & 0x7FFu) | ((kd[8*k+7] & 0x7FFu) << 16));
        *reinterpret_cast<int4*>(dst + 8*k) = w;
    }
}

// np.sum pairwise-8 replication for 64 squares (fp32, no FMA) — keep BIT-IDENTICAL.
__device__ __forceinline__ float np_sq64(const float* __restrict__ v)
{
    float r[8];
    #pragma unroll
    for (int j = 0; j < 8; ++j) r[j] = __fmul_rn(v[j], v[j]);
    #pragma unroll
    for (int i = 1; i < 8; ++i)
        #pragma unroll
        for (int j = 0; j < 8; ++j) r[j] = __fadd_rn(r[j], __fmul_rn(v[8*i+j], v[8*i+j]));
    return __fadd_rn(__fadd_rn(__fadd_rn(r[0],r[1]), __fadd_rn(r[2],r[3])),
                     __fadd_rn(__fadd_rn(r[4],r[5]), __fadd_rn(r[6],r[7])));
}

// ---------------- K2: wave-per-point exact rerank of 128 candidates (2/lane) ----------------
__global__ void k2_refine(const float* __restrict__ x, const unsigned short* __restrict__ cand,
                          int* __restrict__ nbr, int* __restrict__ deg)
{
    const int w    = blockIdx.x * 4 + (threadIdx.x >> 6);   // point id
    const int lane = threadIdx.x & 63;
    const int b    = w >> 11;
    const int ploc = w & (NPTS-1);
    const float* xc = x + (size_t)b * NPTS * CIN;
    const float* xp = xc + (size_t)ploc * CIN;

    float xpl[CIN];
    #pragma unroll
    for (int i = 0; i < CIN/4; ++i) {
        float4 v = *reinterpret_cast<const float4*>(xp + 4*i);
        xpl[4*i+0]=v.x; xpl[4*i+1]=v.y; xpl[4*i+2]=v.z; xpl[4*i+3]=v.w;
    }
    const float sqp = np_sq64(xpl);

    const int q0 = (int)cand[(size_t)w * NCAND + lane];
    const int q1 = (int)cand[(size_t)w * NCAND + 64 + lane];
    const float* xq0 = xc + (size_t)q0 * CIN;
    const float* xq1 = xc + (size_t)q1 * CIN;

    float r0[8], r1[8];
    float dot0 = 0.f, dot1 = 0.f;
    {
        float4 a0 = *reinterpret_cast<const float4*>(xq0 + 0);
        float4 a1 = *reinterpret_cast<const float4*>(xq0 + 4);
        float4 c0 = *reinterpret_cast<const float4*>(xq1 + 0);
        float4 c1 = *reinterpret_cast<const float4*>(xq1 + 4);
        float g0[8] = {a0.x,a0.y,a0.z,a0.w,a1.x,a1.y,a1.z,a1.w};
        float g1[8] = {c0.x,c0.y,c0.z,c0.w,c1.x,c1.y,c1.z,c1.w};
        #pragma unroll
        for (int u = 0; u < 8; ++u) {
            r0[u] = __fmul_rn(g0[u], g0[u]);
            r1[u] = __fmul_rn(g1[u], g1[u]);
            dot0  = __fadd_rn(dot0, __fmul_rn(xpl[u], g0[u]));
            dot1  = __fadd_rn(dot1, __fmul_rn(xpl[u], g1[u]));
        }
    }
    #pragma unroll
    for (int i = 1; i < 8; ++i) {
        float4 a0 = *reinterpret_cast<const float4*>(xq0 + 8*i);
        float4 a1 = *reinterpret_cast<const float4*>(xq0 + 8*i + 4);
        float4 c0 = *reinterpret_cast<const float4*>(xq1 + 8*i);
        float4 c1 = *reinterpret_cast<const float4*>(xq1 + 8*i + 4);
        float g0[8] = {a0.x,a0.y,a0.z,a0.w,a1.x,a1.y,a1.z,a1.w};
        float g1[8] = {c0.x,c0.y,c0.z,c0.w,c1.x,c1.y,c1.z,c1.w};
        #pragma unroll
        for (int u = 0; u < 8; ++u) {
            r0[u] = __fadd_rn(r0[u], __fmul_rn(g0[u], g0[u]));
            r1[u] = __fadd_rn(r1[u], __fmul_rn(g1[u], g1[u]));
            dot0  = __fadd_rn(dot0, __fmul_rn(xpl[8*i+u], g0[u]));
            dot1  = __fadd_rn(dot1, __fmul_rn(xpl[8*i+u], g1[u]));
        }
    }
    const float sqq0 = __fadd_rn(__fadd_rn(__fadd_rn(r0[0],r0[1]), __fadd_rn(r0[2],r0[3])),
                                 __fadd_rn(__fadd_rn(r0[4],r0[5]), __fadd_rn(r0[6],r0[7])));
    const float sqq1 = __fadd_rn(__fadd_rn(__fadd_rn(r1[0],r1[1]), __fadd_rn(r1[2],r1[3])),
                                 __fadd_rn(__fadd_rn(r1[4],r1[5]), __fadd_rn(r1[6],r1[7])));
    float d0 = __fsub_rn(__fadd_rn(sqp, sqq0), __fmul_rn(2.f, dot0));
    float d1 = __fsub_rn(__fadd_rn(sqp, sqq1), __fmul_rn(2.f, dot1));
    if (q0 == ploc) d0 = INFINITY;                  // self-exclusion (exact, loop=False)
    if (q1 == ploc) d1 = INFINITY;

    int rank0 = 0, rank1 = 0;
    for (int s = 0; s < 64; ++s) {                  // exact rank among 128 ((d,idx) total order)
        float e0 = __shfl(d0, s); int p0 = __shfl(q0, s);
        float e1 = __shfl(d1, s); int p1 = __shfl(q1, s);
        rank0 += (e0 < d0 || (e0 == d0 && p0 < q0)) ? 1 : 0;
        rank0 += (e1 < d0 || (e1 == d0 && p1 < q0)) ? 1 : 0;
        rank1 += (e0 < d1 || (e0 == d1 && p0 < q1)) ? 1 : 0;
        rank1 += (e1 < d1 || (e1 == d1 && p1 < q1)) ? 1 : 0;
    }
    if (rank0 < KNN) {
        const int n = b * NPTS + q0;
        nbr[(size_t)w * KNN + rank0] = n;
        atomicAdd(&deg[n], 1);
    }
    if (rank1 < KNN) {
        const int n = b * NPTS + q1;
        nbr[(size_t)w * KNN + rank1] = n;
        atomicAdd(&deg[n], 1);
    }
}

// ---------------- K3s: exclusive prefix scan of deg ----------------
__global__ void k3_scan(const int* __restrict__ deg, int* __restrict__ rowstart, int* __restrict__ wcur)
{
    __shared__ int part[256];
    __shared__ int base[257];
    const int t = threadIdx.x;
    int s = 0;
    for (int i = 0; i < 256; ++i) s += deg[t*256 + i];
    part[t] = s;
    __syncthreads();
    if (t == 0) {
        int acc = 0;
        for (int i = 0; i < 256; ++i) { base[i] = acc; acc += part[i]; }
        base[256] = acc;
    }
    __syncthreads();
    int run = base[t];
    for (int i = 0; i < 256; ++i) {
        rowstart[t*256 + i] = run;
        wcur[t*256 + i] = run;
        run += deg[t*256 + i];
    }
    if (t == 0) rowstart[NTOT] = base[256];
}

// ---------------- K3a: place edges into reverse lists (counter atomics only) ----------------
__global__ void k3_place(const int* __restrict__ nbr, int* __restrict__ wcur, int* __restrict__ rev)
{
    const int e = blockIdx.x * 256 + threadIdx.x;    // edge id
    const int c = e >> 4;                            // center (global point id)
    const int n = nbr[e];                            // neighbor (global point id)
    const int pos = atomicAdd(&wcur[n], 1);
    rev[pos] = c;
}

// ---------------- K3g: gather-max pooled[n] = max over rev(n) of x[c]; empty -> 0 ----------------
__global__ void k3_gather(const float* __restrict__ x, const int* __restrict__ rowstart,
                          const int* __restrict__ rev, float* __restrict__ pooled)
{
    const int n    = blockIdx.x * 4 + (threadIdx.x >> 6);   // point id, one wave each
    const int lane = threadIdx.x & 63;                      // channel
    const int s = rowstart[n];
    const int e = rowstart[n+1];
    float acc = -INFINITY;
    for (int i = s; i < e; ++i) {
        const int c = rev[i];
        acc = fmaxf(acc, x[(size_t)c * CIN + lane]);
    }
    if (e == s) acc = 0.f;                                  // empty row -> 0 (torch_scatter)
    pooled[(size_t)n * CIN + lane] = acc;
}

// ---------------- K4: y = pooled @ W^T + b ----------------
__global__ __launch_bounds__(256,2) void k4_linear(const float* __restrict__ pooled, const float* __restrict__ W,
                                                   const float* __restrict__ bias, float* __restrict__ y)
{
    __shared__ float wl[COUT*68];
    __shared__ float pl[64*68];
    const int t  = threadIdx.x;
    const int r0 = blockIdx.x * 64;
    for (int i = 0; i < (COUT*CIN)/256; ++i) {
        int linear = t + 256*i;
        int c = linear >> 6, k = linear & 63;
        wl[c*68 + k] = W[linear];
    }
    for (int i = 0; i < (64*CIN)/256; ++i) {
        int linear = t + 256*i;
        int r = linear >> 6, k = linear & 63;
        pl[r*68 + k] = pooled[(size_t)(r0 + r)*CIN + k];
    }
    __syncthreads();
    const int tx = t & 15;
    const int ty = t >> 4;
    float acc[4][8];
    #pragma unroll
    for (int j = 0; j < 8; ++j) {
        float bj = bias[tx + 16*j];
        #pragma unroll
        for (int i = 0; i < 4; ++i) acc[i][j] = bj;
    }
    for (int k = 0; k < CIN; k += 4) {
        float4 a[4], bb[8];
        #pragma unroll
        for (int i = 0; i < 4; ++i) a[i]  = *reinterpret_cast<const float4*>(&pl[(ty*4+i)*68 + k]);
        #pragma unroll
        for (int j = 0; j < 8; ++j) bb[j] = *reinterpret_cast<const float4*>(&wl[(tx+16*j)*68 + k]);
        #pragma unroll
        for (int i = 0; i < 4; ++i)
            #pragma unroll
            for (int j = 0; j < 8; ++j) {
                acc[i][j] = fmaf(a[i].x, bb[j].x, acc[i][j]);
                acc[i][j] = fmaf(a[i].y, bb[j].y, acc[i][j]);
                acc[i][j] = fmaf(a[i].z, bb[j].z, acc[i][j]);
                acc[i][j] = fmaf(a[i].w, bb[j].w, acc[i][j]);
            }
    }
    #pragma unroll
    for (int i = 0; i < 4; ++i) {
        float* dst = y + (size_t)(r0 + ty*4 + i) * COUT;
        #pragma unroll
        for (int j = 0; j < 8; ++j) dst[tx + 16*j] = acc[i][j];
    }
}

// ---------------- K5: per-channel sum / sumsq (fp64), 2048 blocks x 32 rows ----------------
__global__ void k5_stats(const float* __restrict__ y, double* __restrict__ sums)
{
    __shared__ double red[512];
    const int t    = threadIdx.x;
    const int ch   = t & 127;
    const int half = t >> 7;
    const size_t base = (size_t)blockIdx.x * 32;
    double s = 0.0, ss = 0.0;
    for (int r = 0; r < 16; ++r) {
        double v = (double)y[(base + (size_t)half*16 + r) * COUT + ch];
        s += v; ss += v*v;
    }
    red[t] = s; red[256 + t] = ss;
    __syncthreads();
    if (half == 0) {
        atomicAdd(&sums[ch],        s  + red[128 + ch]);
        atomicAdd(&sums[COUT + ch], ss + red[256 + 128 + ch]);
    }
}

// ---------------- K6: BN scale/shift ----------------
__global__ void k6_bnparam(const double* __restrict__ sums, const float* __restrict__ gamma,
                           const float* __restrict__ beta, float* __restrict__ scsh)
{
    const int t = threadIdx.x;
    const double mean = sums[t] * (1.0/NTOT);
    const double var  = sums[COUT + t] * (1.0/NTOT) - mean*mean;
    const float inv   = (float)rsqrt(var + 1e-5);
    const float sc    = inv * gamma[t];
    scsh[t]        = sc;
    scsh[COUT + t] = beta[t] - (float)mean * sc;
}

// ---------------- K7: out = relu(y*scale + shift) ----------------
__global__ void k7_bnrelu(const float* __restrict__ y, const float* __restrict__ scsh, float* __restrict__ out)
{
    const int g    = blockIdx.x * blockDim.x + threadIdx.x;
    const int base = g * 4;
    float4 v = *reinterpret_cast<const float4*>(y + base);
    const int ch = base & (COUT-1);
    float4 o;
    o.x = fmaxf(0.f, fmaf(v.x, scsh[ch+0], scsh[COUT+ch+0]));
    o.y = fmaxf(0.f, fmaf(v.y, scsh[ch+1], scsh[COUT+ch+1]));
    o.z = fmaxf(0.f, fmaf(v.z, scsh[ch+2], scsh[COUT+ch+2]));
    o.w = fmaxf(0.f, fmaf(v.w, scsh[ch+3], scsh[COUT+ch+3]));
    *reinterpret_cast<float4*>(out + base) = o;
}

extern "C" void kernel_launch(void* const* d_in, const int* in_sizes, int n_in,
                              void* d_out, int out_size, void* d_ws, size_t ws_size,
                              hipStream_t stream)
{
    const float* x     = (const float*)d_in[0];
    const float* W     = (const float*)d_in[2];
    const float* bias  = (const float*)d_in[3];
    const float* gamma = (const float*)d_in[4];
    const float* beta  = (const float*)d_in[5];
    float* out = (float*)d_out;

    // Workspace (aliasing by liveness; stream order makes each safe):
    //  [0 .. 8.4M)      xhi (k0/k1)           -> pooled [0..16.8M) (k3g, after k1)
    //  [16.8 .. 33.6M)  cand u16 NTOT*128 (k1/k2) -> y [16.8..50.3M) (k4, after k2)
    //  [33.6 .. 37.8M)  nbr (k2/k3a)
    //  [50.3M ..)       CSR scratch, sq, sums, scsh
    char* ws = (char*)d_ws;
    unsigned short* xhi = (unsigned short*)ws;                       // NTOT*64 u16
    float*  pooled = (float*)ws;                                     // NTOT*64 f32 (aliases xhi)
    unsigned short* cand = (unsigned short*)(ws + (size_t)NTOT*CIN*4); // NTOT*128 u16
    float*  y      = (float*)(ws + (size_t)NTOT*CIN*4);              // NTOT*128 f32 (aliases cand/nbr)
    int*    nbr    = (int*)(ws + (size_t)NTOT*(CIN+CIN)*4);          // NTOT*16 int
    char*   csr    = ws + (size_t)NTOT*(CIN+CIN+KNN)*4;              // CSR scratch
    int*    deg      = (int*)csr;                                    // NTOT int
    int*    rowstart = (int*)(csr + (size_t)NTOT*4);                 // NTOT+1 int
    int*    wcur     = (int*)(csr + (size_t)(2*NTOT+1)*4);           // NTOT int
    int*    rev      = (int*)(csr + (size_t)(3*NTOT+1)*4);           // NTOT*KNN int
    float*  sq     = (float*)(ws + (size_t)NTOT*(CIN+COUT)*4);       // NTOT f32
    double* sums   = (double*)(ws + (size_t)NTOT*(CIN+COUT+1)*4);    // 2*COUT f64
    float*  scsh   = (float*)((char*)sums + 2*COUT*sizeof(double));

    hipMemsetAsync(deg, 0, (size_t)NTOT*4, stream);
    hipMemsetAsync(sums, 0, 2*COUT*sizeof(double), stream);

    k0_prep  <<<NTOT/256,   256, 0, stream>>>(x, xhi, sq);
    k1_knn   <<<NTOT/32,    256, 0, stream>>>(xhi, sq, cand);   // 2048 blocks
    k2_refine<<<NTOT/4,     256, 0, stream>>>(x, cand, nbr, deg);

    k3_scan  <<<1,          256, 0, stream>>>(deg, rowstart, wcur);
    k3_place <<<NTOT*KNN/256,256,0, stream>>>(nbr, wcur, rev);
    k3_gather<<<NTOT/4,     256, 0, stream>>>(x, rowstart, rev, pooled);

    k4_linear <<<NTOT/64, 256, 0, stream>>>(pooled, W, bias, y);
    k5_stats  <<<NTOT/32, 256, 0, stream>>>(y, sums);
    k6_bnparam<<<1,      COUT, 0, stream>>>(sums, gamma, beta, scsh);
    k7_bnrelu <<<(NTOT*COUT/4)/256, 256, 0, stream>>>(y, scsh, out);
}

// Round 11
// 624.736 us; speedup vs baseline: 1.4344x; 1.4344x over previous
//
#include <hip/hip_runtime.h>
#include <hip/hip_bf16.h>
#include <math.h>

#define NPTS 2048
#define NCLOUD 32
#define NTOT (NPTS*NCLOUD)
#define CIN 64
#define COUT 128
#define KNN 16
#define KSUB 16            // kept per subset (16 = structural superset guarantee)
#define NCAND 128          // 8 subsets (2 col-halves x 4 quads) * 16
#define PREF_MARGIN 0.6f   // prefilter margin (approx-key err ~0.1 max, need ~2x)

typedef __attribute__((ext_vector_type(8))) short short8v;   // 8 bf16 (4 VGPR)
typedef __attribute__((ext_vector_type(4))) float float4v;   // 4 fp32

__device__ __forceinline__ unsigned short f2bf(float f) {    // RNE float->bf16
    unsigned u = __float_as_uint(f);
    return (unsigned short)((u + 0x7fffu + ((u >> 16) & 1u)) >> 16);
}
__device__ __forceinline__ unsigned fenc(float f) {          // monotone float->uint
    unsigned u = __float_as_uint(f);
    return u ^ (unsigned)(((int)u >> 31) | 0x80000000);
}
__device__ __forceinline__ float fdec(unsigned u) {          // inverse of fenc
    unsigned m = (unsigned)(((int)(~u) >> 31)) | 0x80000000u;
    return __uint_as_float(u ^ m);
}

// np.sum pairwise-8 replication for 64 squares (fp32, no FMA) — BIT-IDENTICAL recipe.
__device__ __forceinline__ float np_sq64(const float* __restrict__ v)
{
    float r[8];
    #pragma unroll
    for (int j = 0; j < 8; ++j) r[j] = __fmul_rn(v[j], v[j]);
    #pragma unroll
    for (int i = 1; i < 8; ++i)
        #pragma unroll
        for (int j = 0; j < 8; ++j) r[j] = __fadd_rn(r[j], __fmul_rn(v[8*i+j], v[8*i+j]));
    return __fadd_rn(__fadd_rn(__fadd_rn(r[0],r[1]), __fadd_rn(r[2],r[3])),
                     __fadd_rn(__fadd_rn(r[4],r[5]), __fadd_rn(r[6],r[7])));
}

// ---------------- K0: bf16 hi plane + np-faithful |q|^2 ----------------
__global__ void k0_prep(const float* __restrict__ x, unsigned short* __restrict__ xhi,
                        float* __restrict__ sq)
{
    const int p = blockIdx.x * 256 + threadIdx.x;
    const float* src = x + (size_t)p * CIN;
    float e[CIN];
    #pragma unroll
    for (int i = 0; i < 8; ++i) {
        float4 v0 = *reinterpret_cast<const float4*>(src + 8*i);
        float4 v1 = *reinterpret_cast<const float4*>(src + 8*i + 4);
        e[8*i+0]=v0.x; e[8*i+1]=v0.y; e[8*i+2]=v0.z; e[8*i+3]=v0.w;
        e[8*i+4]=v1.x; e[8*i+5]=v1.y; e[8*i+6]=v1.z; e[8*i+7]=v1.w;
        short8v h;
        #pragma unroll
        for (int u = 0; u < 8; ++u) h[u] = (short)f2bf(e[8*i+u]);
        *reinterpret_cast<short8v*>(xhi + (size_t)p*CIN + 8*i) = h;
    }
    sq[p] = np_sq64(e);   // np-faithful (used by BOTH k1 ranking and k2 exact d)
}

// ---------------- K1: MFMA swapped-operand KNN + batched bitonic top-16 ----------------
// 2048 blocks (8 waves/SIMD); stores RAW packed keys (approx dist | 11-bit local id).
__global__ __launch_bounds__(256,1) void k1_knn(const unsigned short* __restrict__ xhi,
                                                const float* __restrict__ sq,
                                                unsigned* __restrict__ cand)
{
    const int wid  = ((blockIdx.x & 7) << 8) + (blockIdx.x >> 3);  // XCD swizzle
    const int o    = wid >> 1;           // row group (64 rows)
    const int half = wid & 1;            // column half
    const int wave = threadIdx.x >> 6;
    const int lane = threadIdx.x & 63;
    const int j    = lane & 15;
    const int quad = lane >> 4;
    const int rowglob = o*64 + wave*16 + j;
    const int cbase   = (rowglob >> 11) << 11;     // cloud base point id

    short8v bhi[2];
    #pragma unroll
    for (int kk = 0; kk < 2; ++kk)
        bhi[kk] = *reinterpret_cast<const short8v*>(xhi + (size_t)rowglob*CIN + quad*8 + kk*32);

    unsigned kd[KSUB];                 // sorted DESC: kd[0] = worst kept
    #pragma unroll
    for (int k = 0; k < KSUB; ++k) kd[k] = 0xFFFFFFFFu;

    for (int it4 = 0; it4 < 16; ++it4) {           // 16 outer iters x 64 cols
        unsigned key[16];
        #pragma unroll
        for (int sub = 0; sub < 4; ++sub) {
            const int colb = half*1024 + it4*64 + sub*16;
            const size_t abase = (size_t)(cbase + colb + j)*CIN + quad*8;
            const short8v ahi0 = *reinterpret_cast<const short8v*>(xhi + abase);
            const short8v ahi1 = *reinterpret_cast<const short8v*>(xhi + abase + 32);

            float4v acc0 = {0.f,0.f,0.f,0.f}, acc1 = {0.f,0.f,0.f,0.f};
            acc0 = __builtin_amdgcn_mfma_f32_16x16x32_bf16(ahi0, bhi[0], acc0, 0,0,0);
            acc1 = __builtin_amdgcn_mfma_f32_16x16x32_bf16(ahi1, bhi[1], acc1, 0,0,0);

            const float4v sqv = *reinterpret_cast<const float4v*>(sq + cbase + colb + quad*4);
            const unsigned idxbase = (unsigned)(colb + quad*4);
            #pragma unroll
            for (int r = 0; r < 4; ++r) {
                const float s = fmaf(-2.f, acc0[r] + acc1[r], sqv[r]);
                key[sub*4 + r] = (fenc(s) & 0xFFFFF800u) | (idxbase + r);
            }
        }

        // bitonic sort key[16] ascending
        #pragma unroll
        for (int k = 2; k <= 16; k <<= 1) {
            #pragma unroll
            for (int jj = k >> 1; jj > 0; jj >>= 1) {
                #pragma unroll
                for (int i = 0; i < 16; ++i) {
                    const int l = i ^ jj;
                    if (l > i) {
                        const bool asc = ((i & k) == 0);
                        const unsigned a = key[i], b = key[l];
                        const unsigned mn = min(a, b), mx = max(a, b);
                        key[i] = asc ? mn : mx;
                        key[l] = asc ? mx : mn;
                    }
                }
            }
        }
        // half-cleaner + merge back to desc
        #pragma unroll
        for (int i = 0; i < 16; ++i) kd[i] = min(kd[i], key[i]);
        #pragma unroll
        for (int jj = 8; jj > 0; jj >>= 1) {
            #pragma unroll
            for (int i = 0; i < 16; ++i) {
                const int l = i ^ jj;
                if (l > i) {
                    const unsigned a = kd[i], b = kd[l];
                    kd[i] = max(a, b); kd[l] = min(a, b);
                }
            }
        }
    }
    unsigned* dst = cand + (size_t)rowglob*NCAND + half*64 + quad*KSUB;
    #pragma unroll
    for (int k = 0; k < 4; ++k) {
        int4 w = { (int)kd[4*k+0], (int)kd[4*k+1], (int)kd[4*k+2], (int)kd[4*k+3] };
        *reinterpret_cast<int4*>(dst + 4*k) = w;
    }
}

// ---------------- K2: prefilter (radix-ballot 16th non-self key + margin) -> compact -> exact rerank ----------------
__global__ void k2_refine(const float* __restrict__ x, const float* __restrict__ sq,
                          const unsigned* __restrict__ cand,
                          int* __restrict__ nbr, int* __restrict__ deg)
{
    __shared__ int sb[4][64];
    const int wv   = threadIdx.x >> 6;
    const int w    = blockIdx.x * 4 + wv;                   // point id
    const int lane = threadIdx.x & 63;
    const int b    = w >> 11;
    const int ploc = w & (NPTS-1);
    const int cbase = b * NPTS;
    const float* xc = x + (size_t)cbase * CIN;
    const float* xp = xc + (size_t)ploc * CIN;

    // --- prefilter on approx keys (self masked out BEFORE the radix search) ---
    unsigned k0v = cand[(size_t)w * NCAND + lane];
    unsigned k1v = cand[(size_t)w * NCAND + 64 + lane];
    if ((int)(k0v & 0x7FFu) == ploc) k0v = 0xFFFFFFFFu;     // self never a candidate
    if ((int)(k1v & 0x7FFu) == ploc) k1v = 0xFFFFFFFFu;

    unsigned T = 0;                          // radix search: 16th smallest non-self key
    #pragma unroll
    for (int bit = 31; bit >= 11; --bit) {
        const unsigned trial = T | (1u << bit);
        const int cnt = __popcll(__ballot(k0v < trial)) + __popcll(__ballot(k1v < trial));
        if (cnt < 16) T = trial;
    }
    const float d16 = fdec(T);                              // T low 11 bits = 0
    const unsigned Tk = (fenc(d16 + PREF_MARGIN) & 0xFFFFF800u) | 0x7FFu;  // inclusive

    const bool s0 = (k0v <= Tk), s1 = (k1v <= Tk);
    const unsigned long long lmask = (1ull << lane) - 1ull;
    const unsigned long long m0 = __ballot(s0);
    const int n0 = __popcll(m0);
    if (s0) { int i0 = __popcll(m0 & lmask);       if (i0 < 64) sb[wv][i0] = (int)(k0v & 0x7FFu); }
    const unsigned long long m1 = __ballot(s1);
    if (s1) { int i1 = n0 + __popcll(m1 & lmask);  if (i1 < 64) sb[wv][i1] = (int)(k1v & 0x7FFu); }
    const int n = min(n0 + __popcll(m1), 64);      // n >= 16 structurally; ~20 typically
    __syncthreads();

    // --- exact np-faithful distance for survivors (1 chain/lane) ---
    float xpl[CIN];
    #pragma unroll
    for (int i = 0; i < CIN/4; ++i) {
        float4 v = *reinterpret_cast<const float4*>(xp + 4*i);
        xpl[4*i+0]=v.x; xpl[4*i+1]=v.y; xpl[4*i+2]=v.z; xpl[4*i+3]=v.w;
    }
    const float sqp = sq[w];                       // np_sq64(xp), precomputed in k0

    const int qloc = (lane < n) ? sb[wv][lane] : 0;
    const float* xq = xc + (size_t)qloc * CIN;
    float dot = 0.f;                               // sequential fp32, no FMA (verified recipe)
    #pragma unroll
    for (int i = 0; i < 8; ++i) {
        float4 v0 = *reinterpret_cast<const float4*>(xq + 8*i);
        float4 v1 = *reinterpret_cast<const float4*>(xq + 8*i + 4);
        float g[8] = {v0.x,v0.y,v0.z,v0.w,v1.x,v1.y,v1.z,v1.w};
        #pragma unroll
        for (int u = 0; u < 8; ++u)
            dot = __fadd_rn(dot, __fmul_rn(xpl[8*i+u], g[u]));
    }
    const float sqq = sq[cbase + qloc];            // np_sq64(xq), precomputed
    float d = __fsub_rn(__fadd_rn(sqp, sqq), __fmul_rn(2.f, dot));
    int qcmp = qloc;
    if (lane >= n) { d = INFINITY; qcmp = 0x7fffffff; }

    int rank = 0;
    for (int s = 0; s < n; ++s) {                  // exact (d, idx) total-order rank
        const float ds = __shfl(d, s);
        const int   qs = __shfl(qcmp, s);
        rank += (ds < d || (ds == d && qs < qcmp)) ? 1 : 0;
    }
    if (lane < n && rank < KNN) {
        const int ng = cbase + qloc;
        nbr[(size_t)w * KNN + rank] = ng;
        atomicAdd(&deg[ng], 1);
    }
}

// ---------------- K3s: exclusive prefix scan; writes rowstart, cursor back into deg ----------------
__global__ void k3_scan(int* __restrict__ deg, int* __restrict__ rowstart)
{
    __shared__ int part[256];
    __shared__ int base[257];
    const int t = threadIdx.x;
    int s = 0;
    for (int i = 0; i < 256; ++i) s += deg[t*256 + i];
    part[t] = s;
    __syncthreads();
    if (t == 0) {
        int acc = 0;
        for (int i = 0; i < 256; ++i) { base[i] = acc; acc += part[i]; }
        base[256] = acc;
    }
    __syncthreads();
    int run = base[t];
    for (int i = 0; i < 256; ++i) {
        const int dv = deg[t*256 + i];
        rowstart[t*256 + i] = run;
        deg[t*256 + i] = run;          // deg becomes the write cursor for k3_place
        run += dv;
    }
    if (t == 0) rowstart[NTOT] = base[256];
}

// ---------------- K3a: place edges into reverse lists (counter atomics only) ----------------
__global__ void k3_place(const int* __restrict__ nbr, int* __restrict__ wcur, int* __restrict__ rev)
{
    const int e = blockIdx.x * 256 + threadIdx.x;
    const int c = e >> 4;
    const int n = nbr[e];
    const int pos = atomicAdd(&wcur[n], 1);
    rev[pos] = c;
}

// ---------------- K3g: gather-max pooled[n]; empty -> 0 ----------------
__global__ void k3_gather(const float* __restrict__ x, const int* __restrict__ rowstart,
                          const int* __restrict__ rev, float* __restrict__ pooled)
{
    const int n    = blockIdx.x * 4 + (threadIdx.x >> 6);
    const int lane = threadIdx.x & 63;
    const int s = rowstart[n];
    const int e = rowstart[n+1];
    float acc = -INFINITY;
    for (int i = s; i < e; ++i) {
        const int c = rev[i];
        acc = fmaxf(acc, x[(size_t)c * CIN + lane]);
    }
    if (e == s) acc = 0.f;
    pooled[(size_t)n * CIN + lane] = acc;
}

// ---------------- K4: y = pooled @ W^T + b ----------------
__global__ __launch_bounds__(256,2) void k4_linear(const float* __restrict__ pooled, const float* __restrict__ W,
                                                   const float* __restrict__ bias, float* __restrict__ y)
{
    __shared__ float wl[COUT*68];
    __shared__ float pl[64*68];
    const int t  = threadIdx.x;
    const int r0 = blockIdx.x * 64;
    for (int i = 0; i < (COUT*CIN)/256; ++i) {
        int linear = t + 256*i;
        int c = linear >> 6, k = linear & 63;
        wl[c*68 + k] = W[linear];
    }
    for (int i = 0; i < (64*CIN)/256; ++i) {
        int linear = t + 256*i;
        int r = linear >> 6, k = linear & 63;
        pl[r*68 + k] = pooled[(size_t)(r0 + r)*CIN + k];
    }
    __syncthreads();
    const int tx = t & 15;
    const int ty = t >> 4;
    float acc[4][8];
    #pragma unroll
    for (int j = 0; j < 8; ++j) {
        float bj = bias[tx + 16*j];
        #pragma unroll
        for (int i = 0; i < 4; ++i) acc[i][j] = bj;
    }
    for (int k = 0; k < CIN; k += 4) {
        float4 a[4], bb[8];
        #pragma unroll
        for (int i = 0; i < 4; ++i) a[i]  = *reinterpret_cast<const float4*>(&pl[(ty*4+i)*68 + k]);
        #pragma unroll
        for (int j = 0; j < 8; ++j) bb[j] = *reinterpret_cast<const float4*>(&wl[(tx+16*j)*68 + k]);
        #pragma unroll
        for (int i = 0; i < 4; ++i)
            #pragma unroll
            for (int j = 0; j < 8; ++j) {
                acc[i][j] = fmaf(a[i].x, bb[j].x, acc[i][j]);
                acc[i][j] = fmaf(a[i].y, bb[j].y, acc[i][j]);
                acc[i][j] = fmaf(a[i].z, bb[j].z, acc[i][j]);
                acc[i][j] = fmaf(a[i].w, bb[j].w, acc[i][j]);
            }
    }
    #pragma unroll
    for (int i = 0; i < 4; ++i) {
        float* dst = y + (size_t)(r0 + ty*4 + i) * COUT;
        #pragma unroll
        for (int j = 0; j < 8; ++j) dst[tx + 16*j] = acc[i][j];
    }
}

// ---------------- K5: per-channel sum / sumsq (fp64) ----------------
__global__ void k5_stats(const float* __restrict__ y, double* __restrict__ sums)
{
    __shared__ double red[512];
    const int t    = threadIdx.x;
    const int ch   = t & 127;
    const int half = t >> 7;
    const size_t base = (size_t)blockIdx.x * 32;
    double s = 0.0, ss = 0.0;
    for (int r = 0; r < 16; ++r) {
        double v = (double)y[(base + (size_t)half*16 + r) * COUT + ch];
        s += v; ss += v*v;
    }
    red[t] = s; red[256 + t] = ss;
    __syncthreads();
    if (half == 0) {
        atomicAdd(&sums[ch],        s  + red[128 + ch]);
        atomicAdd(&sums[COUT + ch], ss + red[256 + 128 + ch]);
    }
}

// ---------------- K6: BN scale/shift ----------------
__global__ void k6_bnparam(const double* __restrict__ sums, const float* __restrict__ gamma,
                           const float* __restrict__ beta, float* __restrict__ scsh)
{
    const int t = threadIdx.x;
    const double mean = sums[t] * (1.0/NTOT);
    const double var  = sums[COUT + t] * (1.0/NTOT) - mean*mean;
    const float inv   = (float)rsqrt(var + 1e-5);
    const float sc    = inv * gamma[t];
    scsh[t]        = sc;
    scsh[COUT + t] = beta[t] - (float)mean * sc;
}

// ---------------- K7: out = relu(y*scale + shift) ----------------
__global__ void k7_bnrelu(const float* __restrict__ y, const float* __restrict__ scsh, float* __restrict__ out)
{
    const int g    = blockIdx.x * blockDim.x + threadIdx.x;
    const int base = g * 4;
    float4 v = *reinterpret_cast<const float4*>(y + base);
    const int ch = base & (COUT-1);
    float4 o;
    o.x = fmaxf(0.f, fmaf(v.x, scsh[ch+0], scsh[COUT+ch+0]));
    o.y = fmaxf(0.f, fmaf(v.y, scsh[ch+1], scsh[COUT+ch+1]));
    o.z = fmaxf(0.f, fmaf(v.z, scsh[ch+2], scsh[COUT+ch+2]));
    o.w = fmaxf(0.f, fmaf(v.w, scsh[ch+3], scsh[COUT+ch+3]));
    *reinterpret_cast<float4*>(out + base) = o;
}

extern "C" void kernel_launch(void* const* d_in, const int* in_sizes, int n_in,
                              void* d_out, int out_size, void* d_ws, size_t ws_size,
                              hipStream_t stream)
{
    const float* x     = (const float*)d_in[0];
    const float* W     = (const float*)d_in[2];
    const float* bias  = (const float*)d_in[3];
    const float* gamma = (const float*)d_in[4];
    const float* beta  = (const float*)d_in[5];
    float* out = (float*)d_out;

    // Workspace — explicit 16B-aligned byte offsets (all products of NTOT are 16B-aligned):
    //  [0, NTOT*128)          xhi (k0->k1)      }  pooled [0, NTOT*256) (k3g->k4) aliases
    //  [NTOT*256, +NTOT*512)  cand (k1->k2)     }  y (k4->k5,k7) aliases
    //  [NTOT*768, +NTOT*64)   nbr (k2->k3a)
    //  [NTOT*832, +NTOT*4)    deg -> wcur (k2->k3s->k3a)
    //  [.., +(NTOT+4)*4)      rowstart (k3s->k3g)
    //  [.., +NTOT*64)         rev (k3a->k3g)
    //  [.., +NTOT*4)          sq (k0->k2)
    //  [.., +2048)            sums (f64, 16B-aligned — round-10 crash was 4-mod-8 sums)
    //  [.., +1024)            scsh
    char* ws = (char*)d_ws;
    unsigned short* xhi = (unsigned short*)ws;
    float*    pooled   = (float*)ws;
    unsigned* cand     = (unsigned*)(ws + (size_t)NTOT*256);
    float*    y        = (float*)(ws + (size_t)NTOT*256);
    int*      nbr      = (int*)(ws + (size_t)NTOT*768);
    int*      deg      = (int*)(ws + (size_t)NTOT*832);            // becomes wcur after k3_scan
    int*      rowstart = (int*)(ws + (size_t)NTOT*836);
    int*      rev      = (int*)(ws + (size_t)NTOT*840 + 16);
    float*    sq       = (float*)(ws + (size_t)NTOT*904 + 16);
    double*   sums     = (double*)(ws + (size_t)NTOT*908 + 16);    // 16B aligned
    float*    scsh     = (float*)(ws + (size_t)NTOT*908 + 16 + 2048);

    hipMemsetAsync(deg, 0, (size_t)NTOT*4, stream);
    hipMemsetAsync(sums, 0, 2*COUT*sizeof(double), stream);

    k0_prep  <<<NTOT/256,   256, 0, stream>>>(x, xhi, sq);
    k1_knn   <<<NTOT/32,    256, 0, stream>>>(xhi, sq, cand);   // 2048 blocks
    k2_refine<<<NTOT/4,     256, 0, stream>>>(x, sq, cand, nbr, deg);

    k3_scan  <<<1,          256, 0, stream>>>(deg, rowstart);
    k3_place <<<NTOT*KNN/256,256,0, stream>>>(nbr, deg, rev);
    k3_gather<<<NTOT/4,     256, 0, stream>>>(x, rowstart, rev, pooled);

    k4_linear <<<NTOT/64, 256, 0, stream>>>(pooled, W, bias, y);
    k5_stats  <<<NTOT/32, 256, 0, stream>>>(y, sums);
    k6_bnparam<<<1,      COUT, 0, stream>>>(sums, gamma, beta, scsh);
    k7_bnrelu <<<(NTOT*COUT/4)/256, 256, 0, stream>>>(y, scsh, out);
}

// Round 12
// 495.898 us; speedup vs baseline: 1.8071x; 1.2598x over previous
//
#include <hip/hip_runtime.h>
#include <hip/hip_bf16.h>
#include <math.h>

#define NPTS 2048
#define NCLOUD 32
#define NTOT (NPTS*NCLOUD)
#define CIN 64
#define COUT 128
#define KNN 16
#define KSUB 16            // kept per subset (16 = structural superset guarantee)
#define NCAND 128          // 8 subsets (2 col-halves x 4 quads) * 16
#define PREF_MARGIN 0.6f   // prefilter margin (approx-key err ~0.1 max, need ~2x)

typedef __attribute__((ext_vector_type(8))) short short8v;   // 8 bf16 (4 VGPR)
typedef __attribute__((ext_vector_type(4))) float float4v;   // 4 fp32

__device__ __forceinline__ unsigned short f2bf(float f) {    // RNE float->bf16
    unsigned u = __float_as_uint(f);
    return (unsigned short)((u + 0x7fffu + ((u >> 16) & 1u)) >> 16);
}
__device__ __forceinline__ unsigned fenc(float f) {          // monotone float->uint
    unsigned u = __float_as_uint(f);
    return u ^ (unsigned)(((int)u >> 31) | 0x80000000);
}
__device__ __forceinline__ float fdec(unsigned u) {          // inverse of fenc
    unsigned m = (unsigned)(((int)(~u) >> 31)) | 0x80000000u;
    return __uint_as_float(u ^ m);
}

// np.sum pairwise-8 replication for 64 squares (fp32, no FMA) — BIT-IDENTICAL recipe.
__device__ __forceinline__ float np_sq64(const float* __restrict__ v)
{
    float r[8];
    #pragma unroll
    for (int j = 0; j < 8; ++j) r[j] = __fmul_rn(v[j], v[j]);
    #pragma unroll
    for (int i = 1; i < 8; ++i)
        #pragma unroll
        for (int j = 0; j < 8; ++j) r[j] = __fadd_rn(r[j], __fmul_rn(v[8*i+j], v[8*i+j]));
    return __fadd_rn(__fadd_rn(__fadd_rn(r[0],r[1]), __fadd_rn(r[2],r[3])),
                     __fadd_rn(__fadd_rn(r[4],r[5]), __fadd_rn(r[6],r[7])));
}

// ---------------- K0: bf16 hi plane + np-faithful |q|^2 ----------------
__global__ void k0_prep(const float* __restrict__ x, unsigned short* __restrict__ xhi,
                        float* __restrict__ sq)
{
    const int p = blockIdx.x * 256 + threadIdx.x;
    const float* src = x + (size_t)p * CIN;
    float e[CIN];
    #pragma unroll
    for (int i = 0; i < 8; ++i) {
        float4 v0 = *reinterpret_cast<const float4*>(src + 8*i);
        float4 v1 = *reinterpret_cast<const float4*>(src + 8*i + 4);
        e[8*i+0]=v0.x; e[8*i+1]=v0.y; e[8*i+2]=v0.z; e[8*i+3]=v0.w;
        e[8*i+4]=v1.x; e[8*i+5]=v1.y; e[8*i+6]=v1.z; e[8*i+7]=v1.w;
        short8v h;
        #pragma unroll
        for (int u = 0; u < 8; ++u) h[u] = (short)f2bf(e[8*i+u]);
        *reinterpret_cast<short8v*>(xhi + (size_t)p*CIN + 8*i) = h;
    }
    sq[p] = np_sq64(e);   // np-faithful (used by BOTH k1 ranking and k2 exact d)
}

// ---------------- K1: MFMA swapped-operand KNN + batched bitonic top-16 ----------------
// 2048 blocks (8 waves/SIMD); stores RAW packed keys (approx dist | 11-bit local id).
__global__ __launch_bounds__(256,1) void k1_knn(const unsigned short* __restrict__ xhi,
                                                const float* __restrict__ sq,
                                                unsigned* __restrict__ cand)
{
    const int wid  = ((blockIdx.x & 7) << 8) + (blockIdx.x >> 3);  // XCD swizzle
    const int o    = wid >> 1;           // row group (64 rows)
    const int half = wid & 1;            // column half
    const int wave = threadIdx.x >> 6;
    const int lane = threadIdx.x & 63;
    const int j    = lane & 15;
    const int quad = lane >> 4;
    const int rowglob = o*64 + wave*16 + j;
    const int cbase   = (rowglob >> 11) << 11;     // cloud base point id

    short8v bhi[2];
    #pragma unroll
    for (int kk = 0; kk < 2; ++kk)
        bhi[kk] = *reinterpret_cast<const short8v*>(xhi + (size_t)rowglob*CIN + quad*8 + kk*32);

    unsigned kd[KSUB];                 // sorted DESC: kd[0] = worst kept
    #pragma unroll
    for (int k = 0; k < KSUB; ++k) kd[k] = 0xFFFFFFFFu;

    for (int it4 = 0; it4 < 16; ++it4) {           // 16 outer iters x 64 cols
        unsigned key[16];
        #pragma unroll
        for (int sub = 0; sub < 4; ++sub) {
            const int colb = half*1024 + it4*64 + sub*16;
            const size_t abase = (size_t)(cbase + colb + j)*CIN + quad*8;
            const short8v ahi0 = *reinterpret_cast<const short8v*>(xhi + abase);
            const short8v ahi1 = *reinterpret_cast<const short8v*>(xhi + abase + 32);

            float4v acc0 = {0.f,0.f,0.f,0.f}, acc1 = {0.f,0.f,0.f,0.f};
            acc0 = __builtin_amdgcn_mfma_f32_16x16x32_bf16(ahi0, bhi[0], acc0, 0,0,0);
            acc1 = __builtin_amdgcn_mfma_f32_16x16x32_bf16(ahi1, bhi[1], acc1, 0,0,0);

            const float4v sqv = *reinterpret_cast<const float4v*>(sq + cbase + colb + quad*4);
            const unsigned idxbase = (unsigned)(colb + quad*4);
            #pragma unroll
            for (int r = 0; r < 4; ++r) {
                const float s = fmaf(-2.f, acc0[r] + acc1[r], sqv[r]);
                key[sub*4 + r] = (fenc(s) & 0xFFFFF800u) | (idxbase + r);
            }
        }

        // bitonic sort key[16] ascending
        #pragma unroll
        for (int k = 2; k <= 16; k <<= 1) {
            #pragma unroll
            for (int jj = k >> 1; jj > 0; jj >>= 1) {
                #pragma unroll
                for (int i = 0; i < 16; ++i) {
                    const int l = i ^ jj;
                    if (l > i) {
                        const bool asc = ((i & k) == 0);
                        const unsigned a = key[i], b = key[l];
                        const unsigned mn = min(a, b), mx = max(a, b);
                        key[i] = asc ? mn : mx;
                        key[l] = asc ? mx : mn;
                    }
                }
            }
        }
        // half-cleaner + merge back to desc
        #pragma unroll
        for (int i = 0; i < 16; ++i) kd[i] = min(kd[i], key[i]);
        #pragma unroll
        for (int jj = 8; jj > 0; jj >>= 1) {
            #pragma unroll
            for (int i = 0; i < 16; ++i) {
                const int l = i ^ jj;
                if (l > i) {
                    const unsigned a = kd[i], b = kd[l];
                    kd[i] = max(a, b); kd[l] = min(a, b);
                }
            }
        }
    }
    unsigned* dst = cand + (size_t)rowglob*NCAND + half*64 + quad*KSUB;
    #pragma unroll
    for (int k = 0; k < 4; ++k) {
        int4 w = { (int)kd[4*k+0], (int)kd[4*k+1], (int)kd[4*k+2], (int)kd[4*k+3] };
        *reinterpret_cast<int4*>(dst + 4*k) = w;
    }
}

// ---------------- K2: prefilter (radix-ballot 16th non-self key + margin) -> compact -> exact rerank ----------------
__global__ void k2_refine(const float* __restrict__ x, const float* __restrict__ sq,
                          const unsigned* __restrict__ cand,
                          int* __restrict__ nbr, int* __restrict__ deg)
{
    __shared__ int sb[4][64];
    const int wv   = threadIdx.x >> 6;
    const int w    = blockIdx.x * 4 + wv;                   // point id
    const int lane = threadIdx.x & 63;
    const int b    = w >> 11;
    const int ploc = w & (NPTS-1);
    const int cbase = b * NPTS;
    const float* xc = x + (size_t)cbase * CIN;
    const float* xp = xc + (size_t)ploc * CIN;

    // --- prefilter on approx keys (self masked out BEFORE the radix search) ---
    unsigned k0v = cand[(size_t)w * NCAND + lane];
    unsigned k1v = cand[(size_t)w * NCAND + 64 + lane];
    if ((int)(k0v & 0x7FFu) == ploc) k0v = 0xFFFFFFFFu;     // self never a candidate
    if ((int)(k1v & 0x7FFu) == ploc) k1v = 0xFFFFFFFFu;

    unsigned T = 0;                          // radix search: 16th smallest non-self key
    #pragma unroll
    for (int bit = 31; bit >= 11; --bit) {
        const unsigned trial = T | (1u << bit);
        const int cnt = __popcll(__ballot(k0v < trial)) + __popcll(__ballot(k1v < trial));
        if (cnt < 16) T = trial;
    }
    const float d16 = fdec(T);                              // T low 11 bits = 0
    const unsigned Tk = (fenc(d16 + PREF_MARGIN) & 0xFFFFF800u) | 0x7FFu;  // inclusive

    const bool s0 = (k0v <= Tk), s1 = (k1v <= Tk);
    const unsigned long long lmask = (1ull << lane) - 1ull;
    const unsigned long long m0 = __ballot(s0);
    const int n0 = __popcll(m0);
    if (s0) { int i0 = __popcll(m0 & lmask);       if (i0 < 64) sb[wv][i0] = (int)(k0v & 0x7FFu); }
    const unsigned long long m1 = __ballot(s1);
    if (s1) { int i1 = n0 + __popcll(m1 & lmask);  if (i1 < 64) sb[wv][i1] = (int)(k1v & 0x7FFu); }
    const int n = min(n0 + __popcll(m1), 64);      // n >= 16 structurally; ~20 typically
    __syncthreads();

    // --- exact np-faithful distance for survivors (1 chain/lane) ---
    float xpl[CIN];
    #pragma unroll
    for (int i = 0; i < CIN/4; ++i) {
        float4 v = *reinterpret_cast<const float4*>(xp + 4*i);
        xpl[4*i+0]=v.x; xpl[4*i+1]=v.y; xpl[4*i+2]=v.z; xpl[4*i+3]=v.w;
    }
    const float sqp = sq[w];                       // np_sq64(xp), precomputed in k0

    const int qloc = (lane < n) ? sb[wv][lane] : 0;
    const float* xq = xc + (size_t)qloc * CIN;
    float dot = 0.f;                               // sequential fp32, no FMA (verified recipe)
    #pragma unroll
    for (int i = 0; i < 8; ++i) {
        float4 v0 = *reinterpret_cast<const float4*>(xq + 8*i);
        float4 v1 = *reinterpret_cast<const float4*>(xq + 8*i + 4);
        float g[8] = {v0.x,v0.y,v0.z,v0.w,v1.x,v1.y,v1.z,v1.w};
        #pragma unroll
        for (int u = 0; u < 8; ++u)
            dot = __fadd_rn(dot, __fmul_rn(xpl[8*i+u], g[u]));
    }
    const float sqq = sq[cbase + qloc];            // np_sq64(xq), precomputed
    float d = __fsub_rn(__fadd_rn(sqp, sqq), __fmul_rn(2.f, dot));
    int qcmp = qloc;
    if (lane >= n) { d = INFINITY; qcmp = 0x7fffffff; }

    int rank = 0;
    for (int s = 0; s < n; ++s) {                  // exact (d, idx) total-order rank
        const float ds = __shfl(d, s);
        const int   qs = __shfl(qcmp, s);
        rank += (ds < d || (ds == d && qs < qcmp)) ? 1 : 0;
    }
    if (lane < n && rank < KNN) {
        const int ng = cbase + qloc;
        nbr[(size_t)w * KNN + rank] = ng;
        atomicAdd(&deg[ng], 1);
    }
}

// ---------------- K3s: exclusive prefix scan; writes rowstart, cursor back into deg ----------------
__global__ void k3_scan(int* __restrict__ deg, int* __restrict__ rowstart)
{
    __shared__ int part[256];
    __shared__ int base[257];
    const int t = threadIdx.x;
    int s = 0;
    for (int i = 0; i < 256; ++i) s += deg[t*256 + i];
    part[t] = s;
    __syncthreads();
    if (t == 0) {
        int acc = 0;
        for (int i = 0; i < 256; ++i) { base[i] = acc; acc += part[i]; }
        base[256] = acc;
    }
    __syncthreads();
    int run = base[t];
    for (int i = 0; i < 256; ++i) {
        const int dv = deg[t*256 + i];
        rowstart[t*256 + i] = run;
        deg[t*256 + i] = run;          // deg becomes the write cursor for k3_place
        run += dv;
    }
    if (t == 0) rowstart[NTOT] = base[256];
}

// ---------------- K3a: place edges into reverse lists (counter atomics only) ----------------
__global__ void k3_place(const int* __restrict__ nbr, int* __restrict__ wcur, int* __restrict__ rev)
{
    const int e = blockIdx.x * 256 + threadIdx.x;
    const int c = e >> 4;
    const int n = nbr[e];
    const int pos = atomicAdd(&wcur[n], 1);
    rev[pos] = c;
}

// ---------------- K3g: gather-max, lane-parallel index fetch + 4-wide pipelined rows ----------------
__global__ void k3_gather(const float* __restrict__ x, const int* __restrict__ rowstart,
                          const int* __restrict__ rev, float* __restrict__ pooled)
{
    const int n    = blockIdx.x * 4 + (threadIdx.x >> 6);
    const int lane = threadIdx.x & 63;
    const int s = rowstart[n];
    const int e = rowstart[n+1];
    float a0 = -INFINITY, a1 = -INFINITY, a2 = -INFINITY, a3 = -INFINITY;
    for (int base = s; base < e; base += 64) {
        const int m  = min(64, e - base);
        const int cl = (lane < m) ? rev[base + lane] : 0;   // one coalesced index load
        int k = 0;
        for (; k + 4 <= m; k += 4) {                        // 4 independent row loads in flight
            const int c0 = __shfl(cl, k+0);
            const int c1 = __shfl(cl, k+1);
            const int c2 = __shfl(cl, k+2);
            const int c3 = __shfl(cl, k+3);
            const float v0 = x[(size_t)c0 * CIN + lane];
            const float v1 = x[(size_t)c1 * CIN + lane];
            const float v2 = x[(size_t)c2 * CIN + lane];
            const float v3 = x[(size_t)c3 * CIN + lane];
            a0 = fmaxf(a0, v0); a1 = fmaxf(a1, v1);
            a2 = fmaxf(a2, v2); a3 = fmaxf(a3, v3);
        }
        for (; k < m; ++k) {
            const int c = __shfl(cl, k);
            a0 = fmaxf(a0, x[(size_t)c * CIN + lane]);
        }
    }
    float acc = fmaxf(fmaxf(a0, a1), fmaxf(a2, a3));
    if (e == s) acc = 0.f;                                  // empty row -> 0 (torch_scatter)
    pooled[(size_t)n * CIN + lane] = acc;
}

// ---------------- K4: y = pooled @ W^T + b, with fused per-channel stats (was K5) ----------------
__global__ __launch_bounds__(256,2) void k4_linear(const float* __restrict__ pooled, const float* __restrict__ W,
                                                   const float* __restrict__ bias, float* __restrict__ y,
                                                   double* __restrict__ sums)
{
    __shared__ float wl[COUT*68];
    __shared__ float pl[64*68];     // also reused post-loop as 2x[16][128] stat partials
    const int t  = threadIdx.x;
    const int r0 = blockIdx.x * 64;
    for (int i = 0; i < (COUT*CIN)/256; ++i) {
        int linear = t + 256*i;
        int c = linear >> 6, k = linear & 63;
        wl[c*68 + k] = W[linear];
    }
    for (int i = 0; i < (64*CIN)/256; ++i) {
        int linear = t + 256*i;
        int r = linear >> 6, k = linear & 63;
        pl[r*68 + k] = pooled[(size_t)(r0 + r)*CIN + k];
    }
    __syncthreads();
    const int tx = t & 15;
    const int ty = t >> 4;
    float acc[4][8];
    #pragma unroll
    for (int j = 0; j < 8; ++j) {
        float bj = bias[tx + 16*j];
        #pragma unroll
        for (int i = 0; i < 4; ++i) acc[i][j] = bj;
    }
    for (int k = 0; k < CIN; k += 4) {
        float4 a[4], bb[8];
        #pragma unroll
        for (int i = 0; i < 4; ++i) a[i]  = *reinterpret_cast<const float4*>(&pl[(ty*4+i)*68 + k]);
        #pragma unroll
        for (int j = 0; j < 8; ++j) bb[j] = *reinterpret_cast<const float4*>(&wl[(tx+16*j)*68 + k]);
        #pragma unroll
        for (int i = 0; i < 4; ++i)
            #pragma unroll
            for (int j = 0; j < 8; ++j) {
                acc[i][j] = fmaf(a[i].x, bb[j].x, acc[i][j]);
                acc[i][j] = fmaf(a[i].y, bb[j].y, acc[i][j]);
                acc[i][j] = fmaf(a[i].z, bb[j].z, acc[i][j]);
                acc[i][j] = fmaf(a[i].w, bb[j].w, acc[i][j]);
            }
    }
    #pragma unroll
    for (int i = 0; i < 4; ++i) {
        float* dst = y + (size_t)(r0 + ty*4 + i) * COUT;
        #pragma unroll
        for (int j = 0; j < 8; ++j) dst[tx + 16*j] = acc[i][j];
    }
    // --- fused stats: per-thread 4-row partials -> LDS [16][128] -> 128-lane f64 atomics ---
    __syncthreads();                          // pl reads done; safe to reuse
    #pragma unroll
    for (int j = 0; j < 8; ++j) {
        float s  = ((acc[0][j] + acc[1][j]) + (acc[2][j] + acc[3][j]));
        float ss = ((acc[0][j]*acc[0][j] + acc[1][j]*acc[1][j]) +
                    (acc[2][j]*acc[2][j] + acc[3][j]*acc[3][j]));
        pl[ty*COUT + tx + 16*j]        = s;
        pl[2048 + ty*COUT + tx + 16*j] = ss;
    }
    __syncthreads();
    if (t < COUT) {
        double S = 0.0, SS = 0.0;
        #pragma unroll
        for (int r = 0; r < 16; ++r) {
            S  += (double)pl[r*COUT + t];
            SS += (double)pl[2048 + r*COUT + t];
        }
        atomicAdd(&sums[t], S);
        atomicAdd(&sums[COUT + t], SS);
    }
}

// ---------------- K6: BN scale/shift ----------------
__global__ void k6_bnparam(const double* __restrict__ sums, const float* __restrict__ gamma,
                           const float* __restrict__ beta, float* __restrict__ scsh)
{
    const int t = threadIdx.x;
    const double mean = sums[t] * (1.0/NTOT);
    const double var  = sums[COUT + t] * (1.0/NTOT) - mean*mean;
    const float inv   = (float)rsqrt(var + 1e-5);
    const float sc    = inv * gamma[t];
    scsh[t]        = sc;
    scsh[COUT + t] = beta[t] - (float)mean * sc;
}

// ---------------- K7: out = relu(y*scale + shift) ----------------
__global__ void k7_bnrelu(const float* __restrict__ y, const float* __restrict__ scsh, float* __restrict__ out)
{
    const int g    = blockIdx.x * blockDim.x + threadIdx.x;
    const int base = g * 4;
    float4 v = *reinterpret_cast<const float4*>(y + base);
    const int ch = base & (COUT-1);
    float4 o;
    o.x = fmaxf(0.f, fmaf(v.x, scsh[ch+0], scsh[COUT+ch+0]));
    o.y = fmaxf(0.f, fmaf(v.y, scsh[ch+1], scsh[COUT+ch+1]));
    o.z = fmaxf(0.f, fmaf(v.z, scsh[ch+2], scsh[COUT+ch+2]));
    o.w = fmaxf(0.f, fmaf(v.w, scsh[ch+3], scsh[COUT+ch+3]));
    *reinterpret_cast<float4*>(out + base) = o;
}

extern "C" void kernel_launch(void* const* d_in, const int* in_sizes, int n_in,
                              void* d_out, int out_size, void* d_ws, size_t ws_size,
                              hipStream_t stream)
{
    const float* x     = (const float*)d_in[0];
    const float* W     = (const float*)d_in[2];
    const float* bias  = (const float*)d_in[3];
    const float* gamma = (const float*)d_in[4];
    const float* beta  = (const float*)d_in[5];
    float* out = (float*)d_out;

    // Workspace — explicit 16B-aligned byte offsets:
    //  [0, NTOT*128)          xhi (k0->k1)      }  pooled [0, NTOT*256) (k3g->k4) aliases
    //  [NTOT*256, +NTOT*512)  cand (k1->k2)     }  y (k4->k7) aliases
    //  [NTOT*768, +NTOT*64)   nbr (k2->k3a)
    //  [NTOT*832, +NTOT*4)    deg -> wcur (k2->k3s->k3a)
    //  [.., +(NTOT+4)*4)      rowstart (k3s->k3g)
    //  [.., +NTOT*64)         rev (k3a->k3g)
    //  [.., +NTOT*4)          sq (k0->k2)
    //  [.., +2048)            sums (f64, 16B-aligned)
    //  [.., +1024)            scsh
    char* ws = (char*)d_ws;
    unsigned short* xhi = (unsigned short*)ws;
    float*    pooled   = (float*)ws;
    unsigned* cand     = (unsigned*)(ws + (size_t)NTOT*256);
    float*    y        = (float*)(ws + (size_t)NTOT*256);
    int*      nbr      = (int*)(ws + (size_t)NTOT*768);
    int*      deg      = (int*)(ws + (size_t)NTOT*832);            // becomes wcur after k3_scan
    int*      rowstart = (int*)(ws + (size_t)NTOT*836);
    int*      rev      = (int*)(ws + (size_t)NTOT*840 + 16);
    float*    sq       = (float*)(ws + (size_t)NTOT*904 + 16);
    double*   sums     = (double*)(ws + (size_t)NTOT*908 + 16);    // 16B aligned
    float*    scsh     = (float*)(ws + (size_t)NTOT*908 + 16 + 2048);

    hipMemsetAsync(deg, 0, (size_t)NTOT*4, stream);
    hipMemsetAsync(sums, 0, 2*COUT*sizeof(double), stream);

    k0_prep  <<<NTOT/256,   256, 0, stream>>>(x, xhi, sq);
    k1_knn   <<<NTOT/32,    256, 0, stream>>>(xhi, sq, cand);   // 2048 blocks
    k2_refine<<<NTOT/4,     256, 0, stream>>>(x, sq, cand, nbr, deg);

    k3_scan  <<<1,          256, 0, stream>>>(deg, rowstart);
    k3_place <<<NTOT*KNN/256,256,0, stream>>>(nbr, deg, rev);
    k3_gather<<<NTOT/4,     256, 0, stream>>>(x, rowstart, rev, pooled);

    k4_linear <<<NTOT/64, 256, 0, stream>>>(pooled, W, bias, y, sums);
    k6_bnparam<<<1,      COUT, 0, stream>>>(sums, gamma, beta, scsh);
    k7_bnrelu <<<(NTOT*COUT/4)/256, 256, 0, stream>>>(y, scsh, out);
}

// Round 13
// 493.851 us; speedup vs baseline: 1.8146x; 1.0041x over previous
//
#include <hip/hip_runtime.h>
#include <hip/hip_bf16.h>
#include <math.h>

#define NPTS 2048
#define NCLOUD 32
#define NTOT (NPTS*NCLOUD)
#define CIN 64
#define COUT 128
#define KNN 16
#define NCAND 128          // 8 subsets (2 col-halves x 4 quads) * 16
#define PREF_MARGIN 0.6f   // prefilter margin (approx-key err ~0.3 + key quant 0.125)

typedef __attribute__((ext_vector_type(8))) short short8v;   // 8 bf16 (4 VGPR)
typedef __attribute__((ext_vector_type(4))) float float4v;   // 4 fp32

__device__ __forceinline__ unsigned short f2bf(float f) {    // RNE float->bf16
    unsigned u = __float_as_uint(f);
    return (unsigned short)((u + 0x7fffu + ((u >> 16) & 1u)) >> 16);
}
__device__ __forceinline__ unsigned fenc(float f) {          // monotone float->uint
    unsigned u = __float_as_uint(f);
    return u ^ (unsigned)(((int)u >> 31) | 0x80000000);
}
__device__ __forceinline__ float fdec(unsigned u) {          // inverse of fenc
    unsigned m = (unsigned)(((int)(~u) >> 31)) | 0x80000000u;
    return __uint_as_float(u ^ m);
}

// np.sum pairwise-8 replication for 64 squares (fp32, no FMA) — BIT-IDENTICAL recipe.
__device__ __forceinline__ float np_sq64(const float* __restrict__ v)
{
    float r[8];
    #pragma unroll
    for (int j = 0; j < 8; ++j) r[j] = __fmul_rn(v[j], v[j]);
    #pragma unroll
    for (int i = 1; i < 8; ++i)
        #pragma unroll
        for (int j = 0; j < 8; ++j) r[j] = __fadd_rn(r[j], __fmul_rn(v[8*i+j], v[8*i+j]));
    return __fadd_rn(__fadd_rn(__fadd_rn(r[0],r[1]), __fadd_rn(r[2],r[3])),
                     __fadd_rn(__fadd_rn(r[4],r[5]), __fadd_rn(r[6],r[7])));
}

// ---------------- K0: bf16 hi plane + np-faithful |q|^2 ----------------
__global__ void k0_prep(const float* __restrict__ x, unsigned short* __restrict__ xhi,
                        float* __restrict__ sq)
{
    const int p = blockIdx.x * 256 + threadIdx.x;
    const float* src = x + (size_t)p * CIN;
    float e[CIN];
    #pragma unroll
    for (int i = 0; i < 8; ++i) {
        float4 v0 = *reinterpret_cast<const float4*>(src + 8*i);
        float4 v1 = *reinterpret_cast<const float4*>(src + 8*i + 4);
        e[8*i+0]=v0.x; e[8*i+1]=v0.y; e[8*i+2]=v0.z; e[8*i+3]=v0.w;
        e[8*i+4]=v1.x; e[8*i+5]=v1.y; e[8*i+6]=v1.z; e[8*i+7]=v1.w;
        short8v h;
        #pragma unroll
        for (int u = 0; u < 8; ++u) h[u] = (short)f2bf(e[8*i+u]);
        *reinterpret_cast<short8v*>(xhi + (size_t)p*CIN + 8*i) = h;
    }
    sq[p] = np_sq64(e);
}

// Explicit compare-exchange on key[] (ascending) and kd[] (descending max-first).
#define KA(a,b) { const unsigned _x = key[a], _y = key[b]; key[a] = min(_x,_y); key[b] = max(_x,_y); }
#define KD_(a,b) { const unsigned _x = key[a], _y = key[b]; key[a] = max(_x,_y); key[b] = min(_x,_y); }
#define DD(a,b) { const unsigned _x = kd[a],  _y = kd[b];  kd[a]  = max(_x,_y); kd[b]  = min(_x,_y); }

// ---------------- K1: MFMA swapped-operand KNN + explicit bitonic top-16 ----------------
// 2048 blocks (8 waves/SIMD). Keys: biased fenc(s+16) (always positive -> prefix
// 0xC0000000) with 11-bit col id in the low mantissa bits. Network fully explicit
// (literal indices) to guarantee register allocation (round-12 VGPR=36 implied
// movrel/AGPR-indirect servicing of key[]/kd[]).
__global__ __launch_bounds__(256,1) void k1_knn(const unsigned short* __restrict__ xhi,
                                                const float* __restrict__ sq,
                                                unsigned* __restrict__ cand)
{
    const int wid  = ((blockIdx.x & 7) << 8) + (blockIdx.x >> 3);  // XCD swizzle
    const int o    = wid >> 1;           // row group (64 rows)
    const int half = wid & 1;            // column half
    const int wave = threadIdx.x >> 6;
    const int lane = threadIdx.x & 63;
    const int j    = lane & 15;
    const int quad = lane >> 4;
    const int rowglob = o*64 + wave*16 + j;
    const int cbase   = (rowglob >> 11) << 11;     // cloud base point id

    const short8v bhi0 = *reinterpret_cast<const short8v*>(xhi + (size_t)rowglob*CIN + quad*8);
    const short8v bhi1 = *reinterpret_cast<const short8v*>(xhi + (size_t)rowglob*CIN + quad*8 + 32);

    unsigned kd[16];                   // DESC: kd[0] = worst kept
    #pragma unroll
    for (int k = 0; k < 16; ++k) kd[k] = 0xFFFFFFFFu;

    const unsigned short* pa0 = xhi + (size_t)(cbase + half*1024 + j)*CIN + quad*8;
    const float*          ps0 = sq + cbase + half*1024 + quad*4;

    for (int it4 = 0; it4 < 16; ++it4) {           // 16 batches x 64 cols
        unsigned key[16];
        const unsigned idb = (unsigned)(half*1024 + it4*64 + quad*4) | 0x80000000u;
        #pragma unroll
        for (int sub = 0; sub < 4; ++sub) {
            const unsigned short* pa = pa0 + (size_t)(it4*64 + sub*16)*CIN;
            const short8v a0 = *reinterpret_cast<const short8v*>(pa);
            const short8v a1 = *reinterpret_cast<const short8v*>(pa + 32);
            float4v acc0 = {0.f,0.f,0.f,0.f}, acc1 = {0.f,0.f,0.f,0.f};
            acc0 = __builtin_amdgcn_mfma_f32_16x16x32_bf16(a0, bhi0, acc0, 0,0,0);
            acc1 = __builtin_amdgcn_mfma_f32_16x16x32_bf16(a1, bhi1, acc1, 0,0,0);
            const float4v sqv = *reinterpret_cast<const float4v*>(ps0 + it4*64 + sub*16);
            #pragma unroll
            for (int r = 0; r < 4; ++r) {
                const float s = fmaf(-2.f, acc0[r] + acc1[r], sqv[r] + 16.f);  // biased, > 0
                key[sub*4 + r] = (__float_as_uint(s) & 0xFFFFF800u) | (idb + (unsigned)(sub*16 + r));
            }
        }

        // ---- bitonic sort-16 ascending (explicit, 80 comparators) ----
        KA(0,1)  KD_(2,3)  KA(4,5)  KD_(6,7)  KA(8,9)  KD_(10,11) KA(12,13) KD_(14,15)
        KA(0,2)  KA(1,3)   KD_(4,6) KD_(5,7)  KA(8,10) KA(9,11)   KD_(12,14) KD_(13,15)
        KA(0,1)  KA(2,3)   KD_(4,5) KD_(6,7)  KA(8,9)  KA(10,11)  KD_(12,13) KD_(14,15)
        KA(0,4)  KA(1,5)   KA(2,6)  KA(3,7)   KD_(8,12) KD_(9,13) KD_(10,14) KD_(11,15)
        KA(0,2)  KA(1,3)   KA(4,6)  KA(5,7)   KD_(8,10) KD_(9,11) KD_(12,14) KD_(13,15)
        KA(0,1)  KA(2,3)   KA(4,5)  KA(6,7)   KD_(8,9)  KD_(10,11) KD_(12,13) KD_(14,15)
        KA(0,8)  KA(1,9)   KA(2,10) KA(3,11)  KA(4,12) KA(5,13)   KA(6,14)  KA(7,15)
        KA(0,4)  KA(1,5)   KA(2,6)  KA(3,7)   KA(8,12) KA(9,13)   KA(10,14) KA(11,15)
        KA(0,2)  KA(1,3)   KA(4,6)  KA(5,7)   KA(8,10) KA(9,11)   KA(12,14) KA(13,15)
        KA(0,1)  KA(2,3)   KA(4,5)  KA(6,7)   KA(8,9)  KA(10,11)  KA(12,13) KA(14,15)

        // ---- half-clean: [kd desc | key asc] -> kd = bottom-16 (bitonic) ----
        #pragma unroll
        for (int i = 0; i < 16; ++i) kd[i] = min(kd[i], key[i]);

        // ---- bitonic merge kd back to descending (explicit, 32 comparators) ----
        DD(0,8)  DD(1,9)  DD(2,10) DD(3,11) DD(4,12) DD(5,13) DD(6,14) DD(7,15)
        DD(0,4)  DD(1,5)  DD(2,6)  DD(3,7)  DD(8,12) DD(9,13) DD(10,14) DD(11,15)
        DD(0,2)  DD(1,3)  DD(4,6)  DD(5,7)  DD(8,10) DD(9,11) DD(12,14) DD(13,15)
        DD(0,1)  DD(2,3)  DD(4,5)  DD(6,7)  DD(8,9)  DD(10,11) DD(12,13) DD(14,15)
    }
    unsigned* dst = cand + (size_t)rowglob*NCAND + half*64 + quad*16;
    #pragma unroll
    for (int k = 0; k < 4; ++k) {
        int4 w = { (int)kd[4*k+0], (int)kd[4*k+1], (int)kd[4*k+2], (int)kd[4*k+3] };
        *reinterpret_cast<int4*>(dst + 4*k) = w;
    }
}

// ---------------- K2: prefilter (radix-ballot 16th non-self key + margin) -> compact -> exact rerank ----------------
__global__ void k2_refine(const float* __restrict__ x, const float* __restrict__ sq,
                          const unsigned* __restrict__ cand,
                          int* __restrict__ nbr, int* __restrict__ deg)
{
    __shared__ int sb[4][64];
    const int wv   = threadIdx.x >> 6;
    const int w    = blockIdx.x * 4 + wv;                   // point id
    const int lane = threadIdx.x & 63;
    const int b    = w >> 11;
    const int ploc = w & (NPTS-1);
    const int cbase = b * NPTS;
    const float* xc = x + (size_t)cbase * CIN;
    const float* xp = xc + (size_t)ploc * CIN;

    // --- prefilter on biased approx keys (self masked BEFORE radix) ---
    unsigned k0v = cand[(size_t)w * NCAND + lane];
    unsigned k1v = cand[(size_t)w * NCAND + 64 + lane];
    if ((int)(k0v & 0x7FFu) == ploc) k0v = 0xFFFFFFFFu;
    if ((int)(k1v & 0x7FFu) == ploc) k1v = 0xFFFFFFFFu;

    // biased keys have fixed prefix bits 31..27 = 11000 (s+16 in [15.5, ~512))
    unsigned T = 0xC0000000u;
    #pragma unroll
    for (int bit = 26; bit >= 11; --bit) {
        const unsigned trial = T | (1u << bit);
        const int cnt = __popcll(__ballot(k0v < trial)) + __popcll(__ballot(k1v < trial));
        if (cnt < 16) T = trial;
    }
    const float db16 = fdec(T);                             // biased 16th distance (lower bound)
    const unsigned Tk = (fenc(db16 + PREF_MARGIN) & 0xFFFFF800u) | 0x7FFu;  // inclusive

    const bool s0 = (k0v <= Tk), s1 = (k1v <= Tk);
    const unsigned long long lmask = (1ull << lane) - 1ull;
    const unsigned long long m0 = __ballot(s0);
    const int n0 = __popcll(m0);
    if (s0) { int i0 = __popcll(m0 & lmask);       if (i0 < 64) sb[wv][i0] = (int)(k0v & 0x7FFu); }
    const unsigned long long m1 = __ballot(s1);
    if (s1) { int i1 = n0 + __popcll(m1 & lmask);  if (i1 < 64) sb[wv][i1] = (int)(k1v & 0x7FFu); }
    const int n = min(n0 + __popcll(m1), 64);      // n >= 16 structurally; ~20 typically
    __syncthreads();

    // --- exact np-faithful distance for survivors (1 chain/lane) ---
    float xpl[CIN];
    #pragma unroll
    for (int i = 0; i < CIN/4; ++i) {
        float4 v = *reinterpret_cast<const float4*>(xp + 4*i);
        xpl[4*i+0]=v.x; xpl[4*i+1]=v.y; xpl[4*i+2]=v.z; xpl[4*i+3]=v.w;
    }
    const float sqp = sq[w];                       // np_sq64(xp), precomputed in k0

    const int qloc = (lane < n) ? sb[wv][lane] : 0;
    const float* xq = xc + (size_t)qloc * CIN;
    float dot = 0.f;                               // sequential fp32, no FMA (verified recipe)
    #pragma unroll
    for (int i = 0; i < 8; ++i) {
        float4 v0 = *reinterpret_cast<const float4*>(xq + 8*i);
        float4 v1 = *reinterpret_cast<const float4*>(xq + 8*i + 4);
        float g[8] = {v0.x,v0.y,v0.z,v0.w,v1.x,v1.y,v1.z,v1.w};
        #pragma unroll
        for (int u = 0; u < 8; ++u)
            dot = __fadd_rn(dot, __fmul_rn(xpl[8*i+u], g[u]));
    }
    const float sqq = sq[cbase + qloc];            // np_sq64(xq), precomputed
    float d = __fsub_rn(__fadd_rn(sqp, sqq), __fmul_rn(2.f, dot));
    int qcmp = qloc;
    if (lane >= n) { d = INFINITY; qcmp = 0x7fffffff; }

    int rank = 0;
    for (int s = 0; s < n; ++s) {                  // exact (d, idx) total-order rank
        const float ds = __shfl(d, s);
        const int   qs = __shfl(qcmp, s);
        rank += (ds < d || (ds == d && qs < qcmp)) ? 1 : 0;
    }
    if (lane < n && rank < KNN) {
        const int ng = cbase + qloc;
        nbr[(size_t)w * KNN + rank] = ng;
        atomicAdd(&deg[ng], 1);
    }
}

// ---------------- K3s: exclusive prefix scan; writes rowstart, cursor back into deg ----------------
__global__ void k3_scan(int* __restrict__ deg, int* __restrict__ rowstart)
{
    __shared__ int part[256];
    __shared__ int base[257];
    const int t = threadIdx.x;
    int s = 0;
    for (int i = 0; i < 256; ++i) s += deg[t*256 + i];
    part[t] = s;
    __syncthreads();
    if (t == 0) {
        int acc = 0;
        for (int i = 0; i < 256; ++i) { base[i] = acc; acc += part[i]; }
        base[256] = acc;
    }
    __syncthreads();
    int run = base[t];
    for (int i = 0; i < 256; ++i) {
        const int dv = deg[t*256 + i];
        rowstart[t*256 + i] = run;
        deg[t*256 + i] = run;          // deg becomes the write cursor for k3_place
        run += dv;
    }
    if (t == 0) rowstart[NTOT] = base[256];
}

// ---------------- K3a: place edges into reverse lists (counter atomics only) ----------------
__global__ void k3_place(const int* __restrict__ nbr, int* __restrict__ wcur, int* __restrict__ rev)
{
    const int e = blockIdx.x * 256 + threadIdx.x;
    const int c = e >> 4;
    const int n = nbr[e];
    const int pos = atomicAdd(&wcur[n], 1);
    rev[pos] = c;
}

// ---------------- K3g: gather-max, lane-parallel index fetch + 4-wide pipelined rows ----------------
__global__ void k3_gather(const float* __restrict__ x, const int* __restrict__ rowstart,
                          const int* __restrict__ rev, float* __restrict__ pooled)
{
    const int n    = blockIdx.x * 4 + (threadIdx.x >> 6);
    const int lane = threadIdx.x & 63;
    const int s = rowstart[n];
    const int e = rowstart[n+1];
    float a0 = -INFINITY, a1 = -INFINITY, a2 = -INFINITY, a3 = -INFINITY;
    for (int base = s; base < e; base += 64) {
        const int m  = min(64, e - base);
        const int cl = (lane < m) ? rev[base + lane] : 0;   // one coalesced index load
        int k = 0;
        for (; k + 4 <= m; k += 4) {                        // 4 independent row loads in flight
            const int c0 = __shfl(cl, k+0);
            const int c1 = __shfl(cl, k+1);
            const int c2 = __shfl(cl, k+2);
            const int c3 = __shfl(cl, k+3);
            const float v0 = x[(size_t)c0 * CIN + lane];
            const float v1 = x[(size_t)c1 * CIN + lane];
            const float v2 = x[(size_t)c2 * CIN + lane];
            const float v3 = x[(size_t)c3 * CIN + lane];
            a0 = fmaxf(a0, v0); a1 = fmaxf(a1, v1);
            a2 = fmaxf(a2, v2); a3 = fmaxf(a3, v3);
        }
        for (; k < m; ++k) {
            const int c = __shfl(cl, k);
            a0 = fmaxf(a0, x[(size_t)c * CIN + lane]);
        }
    }
    float acc = fmaxf(fmaxf(a0, a1), fmaxf(a2, a3));
    if (e == s) acc = 0.f;                                  // empty row -> 0 (torch_scatter)
    pooled[(size_t)n * CIN + lane] = acc;
}

// ---------------- K4: y = pooled @ W^T + b, with fused per-channel stats ----------------
__global__ __launch_bounds__(256,2) void k4_linear(const float* __restrict__ pooled, const float* __restrict__ W,
                                                   const float* __restrict__ bias, float* __restrict__ y,
                                                   double* __restrict__ sums)
{
    __shared__ float wl[COUT*68];
    __shared__ float pl[64*68];     // reused post-loop as 2x[16][128] stat partials
    const int t  = threadIdx.x;
    const int r0 = blockIdx.x * 64;
    for (int i = 0; i < (COUT*CIN)/256; ++i) {
        int linear = t + 256*i;
        int c = linear >> 6, k = linear & 63;
        wl[c*68 + k] = W[linear];
    }
    for (int i = 0; i < (64*CIN)/256; ++i) {
        int linear = t + 256*i;
        int r = linear >> 6, k = linear & 63;
        pl[r*68 + k] = pooled[(size_t)(r0 + r)*CIN + k];
    }
    __syncthreads();
    const int tx = t & 15;
    const int ty = t >> 4;
    float acc[4][8];
    #pragma unroll
    for (int j = 0; j < 8; ++j) {
        float bj = bias[tx + 16*j];
        #pragma unroll
        for (int i = 0; i < 4; ++i) acc[i][j] = bj;
    }
    for (int k = 0; k < CIN; k += 4) {
        float4 a[4], bb[8];
        #pragma unroll
        for (int i = 0; i < 4; ++i) a[i]  = *reinterpret_cast<const float4*>(&pl[(ty*4+i)*68 + k]);
        #pragma unroll
        for (int j = 0; j < 8; ++j) bb[j] = *reinterpret_cast<const float4*>(&wl[(tx+16*j)*68 + k]);
        #pragma unroll
        for (int i = 0; i < 4; ++i)
            #pragma unroll
            for (int j = 0; j < 8; ++j) {
                acc[i][j] = fmaf(a[i].x, bb[j].x, acc[i][j]);
                acc[i][j] = fmaf(a[i].y, bb[j].y, acc[i][j]);
                acc[i][j] = fmaf(a[i].z, bb[j].z, acc[i][j]);
                acc[i][j] = fmaf(a[i].w, bb[j].w, acc[i][j]);
            }
    }
    #pragma unroll
    for (int i = 0; i < 4; ++i) {
        float* dst = y + (size_t)(r0 + ty*4 + i) * COUT;
        #pragma unroll
        for (int j = 0; j < 8; ++j) dst[tx + 16*j] = acc[i][j];
    }
    // --- fused stats ---
    __syncthreads();
    #pragma unroll
    for (int j = 0; j < 8; ++j) {
        float s  = ((acc[0][j] + acc[1][j]) + (acc[2][j] + acc[3][j]));
        float ss = ((acc[0][j]*acc[0][j] + acc[1][j]*acc[1][j]) +
                    (acc[2][j]*acc[2][j] + acc[3][j]*acc[3][j]));
        pl[ty*COUT + tx + 16*j]        = s;
        pl[2048 + ty*COUT + tx + 16*j] = ss;
    }
    __syncthreads();
    if (t < COUT) {
        double S = 0.0, SS = 0.0;
        #pragma unroll
        for (int r = 0; r < 16; ++r) {
            S  += (double)pl[r*COUT + t];
            SS += (double)pl[2048 + r*COUT + t];
        }
        atomicAdd(&sums[t], S);
        atomicAdd(&sums[COUT + t], SS);
    }
}

// ---------------- K6: BN scale/shift ----------------
__global__ void k6_bnparam(const double* __restrict__ sums, const float* __restrict__ gamma,
                           const float* __restrict__ beta, float* __restrict__ scsh)
{
    const int t = threadIdx.x;
    const double mean = sums[t] * (1.0/NTOT);
    const double var  = sums[COUT + t] * (1.0/NTOT) - mean*mean;
    const float inv   = (float)rsqrt(var + 1e-5);
    const float sc    = inv * gamma[t];
    scsh[t]        = sc;
    scsh[COUT + t] = beta[t] - (float)mean * sc;
}

// ---------------- K7: out = relu(y*scale + shift) ----------------
__global__ void k7_bnrelu(const float* __restrict__ y, const float* __restrict__ scsh, float* __restrict__ out)
{
    const int g    = blockIdx.x * blockDim.x + threadIdx.x;
    const int base = g * 4;
    float4 v = *reinterpret_cast<const float4*>(y + base);
    const int ch = base & (COUT-1);
    float4 o;
    o.x = fmaxf(0.f, fmaf(v.x, scsh[ch+0], scsh[COUT+ch+0]));
    o.y = fmaxf(0.f, fmaf(v.y, scsh[ch+1], scsh[COUT+ch+1]));
    o.z = fmaxf(0.f, fmaf(v.z, scsh[ch+2], scsh[COUT+ch+2]));
    o.w = fmaxf(0.f, fmaf(v.w, scsh[ch+3], scsh[COUT+ch+3]));
    *reinterpret_cast<float4*>(out + base) = o;
}

extern "C" void kernel_launch(void* const* d_in, const int* in_sizes, int n_in,
                              void* d_out, int out_size, void* d_ws, size_t ws_size,
                              hipStream_t stream)
{
    const float* x     = (const float*)d_in[0];
    const float* W     = (const float*)d_in[2];
    const float* bias  = (const float*)d_in[3];
    const float* gamma = (const float*)d_in[4];
    const float* beta  = (const float*)d_in[5];
    float* out = (float*)d_out;

    // Workspace — explicit 16B-aligned byte offsets (layout identical to round 12):
    char* ws = (char*)d_ws;
    unsigned short* xhi = (unsigned short*)ws;
    float*    pooled   = (float*)ws;
    unsigned* cand     = (unsigned*)(ws + (size_t)NTOT*256);
    float*    y        = (float*)(ws + (size_t)NTOT*256);
    int*      nbr      = (int*)(ws + (size_t)NTOT*768);
    int*      deg      = (int*)(ws + (size_t)NTOT*832);            // becomes wcur after k3_scan
    int*      rowstart = (int*)(ws + (size_t)NTOT*836);
    int*      rev      = (int*)(ws + (size_t)NTOT*840 + 16);
    float*    sq       = (float*)(ws + (size_t)NTOT*904 + 16);
    double*   sums     = (double*)(ws + (size_t)NTOT*908 + 16);    // 16B aligned
    float*    scsh     = (float*)(ws + (size_t)NTOT*908 + 16 + 2048);

    hipMemsetAsync(deg, 0, (size_t)NTOT*4, stream);
    hipMemsetAsync(sums, 0, 2*COUT*sizeof(double), stream);

    k0_prep  <<<NTOT/256,   256, 0, stream>>>(x, xhi, sq);
    k1_knn   <<<NTOT/32,    256, 0, stream>>>(xhi, sq, cand);   // 2048 blocks
    k2_refine<<<NTOT/4,     256, 0, stream>>>(x, sq, cand, nbr, deg);

    k3_scan  <<<1,          256, 0, stream>>>(deg, rowstart);
    k3_place <<<NTOT*KNN/256,256,0, stream>>>(nbr, deg, rev);
    k3_gather<<<NTOT/4,     256, 0, stream>>>(x, rowstart, rev, pooled);

    k4_linear <<<NTOT/64, 256, 0, stream>>>(pooled, W, bias, y, sums);
    k6_bnparam<<<1,      COUT, 0, stream>>>(sums, gamma, beta, scsh);
    k7_bnrelu <<<(NTOT*COUT/4)/256, 256, 0, stream>>>(y, scsh, out);
}

// Round 14
// 474.477 us; speedup vs baseline: 1.8886x; 1.0408x over previous
//
#include <hip/hip_runtime.h>
#include <hip/hip_bf16.h>
#include <math.h>

#define NPTS 2048
#define NCLOUD 32
#define NTOT (NPTS*NCLOUD)
#define CIN 64
#define COUT 128
#define KNN 16
#define NCAND 128          // 8 subsets (2 col-halves x 4 quads) * 16
#define PREF_MARGIN 0.6f   // prefilter margin (approx-key err ~0.3 + key quant)

typedef __attribute__((ext_vector_type(8))) short short8v;   // 8 bf16 (4 VGPR)
typedef __attribute__((ext_vector_type(4))) float float4v;   // 4 fp32

__device__ __forceinline__ unsigned short f2bf(float f) {    // RNE float->bf16
    unsigned u = __float_as_uint(f);
    return (unsigned short)((u + 0x7fffu + ((u >> 16) & 1u)) >> 16);
}
__device__ __forceinline__ unsigned fenc(float f) {          // monotone float->uint
    unsigned u = __float_as_uint(f);
    return u ^ (unsigned)(((int)u >> 31) | 0x80000000);
}
__device__ __forceinline__ float fdec(unsigned u) {          // inverse of fenc
    unsigned m = (unsigned)(((int)(~u) >> 31)) | 0x80000000u;
    return __uint_as_float(u ^ m);
}

// np.sum pairwise-8 replication for 64 squares (fp32, no FMA) — BIT-IDENTICAL recipe.
__device__ __forceinline__ float np_sq64(const float* __restrict__ v)
{
    float r[8];
    #pragma unroll
    for (int j = 0; j < 8; ++j) r[j] = __fmul_rn(v[j], v[j]);
    #pragma unroll
    for (int i = 1; i < 8; ++i)
        #pragma unroll
        for (int j = 0; j < 8; ++j) r[j] = __fadd_rn(r[j], __fmul_rn(v[8*i+j], v[8*i+j]));
    return __fadd_rn(__fadd_rn(__fadd_rn(r[0],r[1]), __fadd_rn(r[2],r[3])),
                     __fadd_rn(__fadd_rn(r[4],r[5]), __fadd_rn(r[6],r[7])));
}

// ---------------- K0: bf16 hi plane + np-faithful |q|^2 (+biased copy) + deg zero ----------------
__global__ void k0_prep(const float* __restrict__ x, unsigned short* __restrict__ xhi,
                        float* __restrict__ sq, float* __restrict__ sqb, int* __restrict__ deg)
{
    const int p = blockIdx.x * 256 + threadIdx.x;
    const float* src = x + (size_t)p * CIN;
    float e[CIN];
    #pragma unroll
    for (int i = 0; i < 8; ++i) {
        float4 v0 = *reinterpret_cast<const float4*>(src + 8*i);
        float4 v1 = *reinterpret_cast<const float4*>(src + 8*i + 4);
        e[8*i+0]=v0.x; e[8*i+1]=v0.y; e[8*i+2]=v0.z; e[8*i+3]=v0.w;
        e[8*i+4]=v1.x; e[8*i+5]=v1.y; e[8*i+6]=v1.z; e[8*i+7]=v1.w;
        short8v h;
        #pragma unroll
        for (int u = 0; u < 8; ++u) h[u] = (short)f2bf(e[8*i+u]);
        *reinterpret_cast<short8v*>(xhi + (size_t)p*CIN + 8*i) = h;
    }
    const float s = np_sq64(e);
    sq[p]  = s;           // exact (k2)
    sqb[p] = s + 16.f;    // biased (k1 keys; always > 0)
    deg[p] = 0;           // replaces memset
}

// Comparators: KA = ascending on key[], DD = descending on kd[].
#define KA(a,b) { const unsigned _x = key[a], _y = key[b]; key[a] = min(_x,_y); key[b] = max(_x,_y); }
#define DD(a,b) { const unsigned _x = kd[a],  _y = kd[b];  kd[a]  = max(_x,_y); kd[b]  = min(_x,_y); }

// ---------------- K1: MFMA swapped-operand KNN + Batcher-63 top-16 + sub0 prefetch ----------------
__global__ __launch_bounds__(256,1) void k1_knn(const unsigned short* __restrict__ xhi,
                                                const float* __restrict__ sqb,
                                                unsigned* __restrict__ cand)
{
    const int wid  = ((blockIdx.x & 7) << 8) + (blockIdx.x >> 3);  // XCD swizzle
    const int o    = wid >> 1;           // row group (64 rows)
    const int half = wid & 1;            // column half
    const int wave = threadIdx.x >> 6;
    const int lane = threadIdx.x & 63;
    const int j    = lane & 15;
    const int quad = lane >> 4;
    const int rowglob = o*64 + wave*16 + j;
    const int cbase   = (rowglob >> 11) << 11;     // cloud base point id

    const short8v bhi0 = *reinterpret_cast<const short8v*>(xhi + (size_t)rowglob*CIN + quad*8);
    const short8v bhi1 = *reinterpret_cast<const short8v*>(xhi + (size_t)rowglob*CIN + quad*8 + 32);

    unsigned kd[16];                   // DESC: kd[0] = worst kept
    #pragma unroll
    for (int k = 0; k < 16; ++k) kd[k] = 0xFFFFFFFFu;

    const unsigned short* pa0 = xhi + (size_t)(cbase + half*1024 + j)*CIN + quad*8;
    const float*          ps0 = sqb + cbase + half*1024 + quad*4;

    // prefetch sub0 of batch 0
    short8v pfa0 = *reinterpret_cast<const short8v*>(pa0);
    short8v pfa1 = *reinterpret_cast<const short8v*>(pa0 + 32);

    for (int it4 = 0; it4 < 16; ++it4) {           // 16 batches x 64 cols
        unsigned key[16];
        const unsigned idb = (unsigned)(half*1024 + it4*64 + quad*4) | 0x80000000u;

        // ---- sub 0 (from prefetch regs) ----
        {
            float4v acc0 = {0.f,0.f,0.f,0.f}, acc1 = {0.f,0.f,0.f,0.f};
            acc0 = __builtin_amdgcn_mfma_f32_16x16x32_bf16(pfa0, bhi0, acc0, 0,0,0);
            acc1 = __builtin_amdgcn_mfma_f32_16x16x32_bf16(pfa1, bhi1, acc1, 0,0,0);
            const float4v sqv = *reinterpret_cast<const float4v*>(ps0 + it4*64);
            #pragma unroll
            for (int r = 0; r < 4; ++r) {
                const float s = fmaf(-2.f, acc0[r] + acc1[r], sqv[r]);
                key[r] = (__float_as_uint(s) & 0xFFFFF800u) | (idb + (unsigned)r);
            }
        }
        // ---- prefetch sub0 of next batch (covers the network below) ----
        {
            const int nxt = (it4 < 15) ? it4 + 1 : 15;
            const unsigned short* pan = pa0 + (size_t)(nxt*64)*CIN;
            pfa0 = *reinterpret_cast<const short8v*>(pan);
            pfa1 = *reinterpret_cast<const short8v*>(pan + 32);
        }
        // ---- subs 1..3 inline ----
        #pragma unroll
        for (int sub = 1; sub < 4; ++sub) {
            const unsigned short* pa = pa0 + (size_t)(it4*64 + sub*16)*CIN;
            const short8v a0 = *reinterpret_cast<const short8v*>(pa);
            const short8v a1 = *reinterpret_cast<const short8v*>(pa + 32);
            float4v acc0 = {0.f,0.f,0.f,0.f}, acc1 = {0.f,0.f,0.f,0.f};
            acc0 = __builtin_amdgcn_mfma_f32_16x16x32_bf16(a0, bhi0, acc0, 0,0,0);
            acc1 = __builtin_amdgcn_mfma_f32_16x16x32_bf16(a1, bhi1, acc1, 0,0,0);
            const float4v sqv = *reinterpret_cast<const float4v*>(ps0 + it4*64 + sub*16);
            #pragma unroll
            for (int r = 0; r < 4; ++r) {
                const float s = fmaf(-2.f, acc0[r] + acc1[r], sqv[r]);
                key[sub*4 + r] = (__float_as_uint(s) & 0xFFFFF800u) | (idb + (unsigned)(sub*16 + r));
            }
        }

        // ---- Batcher odd-even mergesort-16 ascending (63 comparators) ----
        // sort-8 of [0..7]
        KA(0,1) KA(2,3) KA(4,5) KA(6,7)
        KA(0,2) KA(1,3) KA(4,6) KA(5,7)
        KA(1,2) KA(5,6)
        KA(0,4) KA(1,5) KA(2,6) KA(3,7)
        KA(2,4) KA(3,5)
        KA(1,2) KA(3,4) KA(5,6)
        // sort-8 of [8..15]
        KA(8,9) KA(10,11) KA(12,13) KA(14,15)
        KA(8,10) KA(9,11) KA(12,14) KA(13,15)
        KA(9,10) KA(13,14)
        KA(8,12) KA(9,13) KA(10,14) KA(11,15)
        KA(10,12) KA(11,13)
        KA(9,10) KA(11,12) KA(13,14)
        // odd-even merge(8,8)
        KA(0,8) KA(1,9) KA(2,10) KA(3,11) KA(4,12) KA(5,13) KA(6,14) KA(7,15)
        KA(4,8) KA(5,9) KA(6,10) KA(7,11)
        KA(2,4) KA(3,5) KA(6,8) KA(7,9) KA(10,12) KA(11,13)
        KA(1,2) KA(3,4) KA(5,6) KA(7,8) KA(9,10) KA(11,12) KA(13,14)

        // ---- half-clean: [kd desc | key asc] -> kd = bottom-16 (bitonic) ----
        #pragma unroll
        for (int i = 0; i < 16; ++i) kd[i] = min(kd[i], key[i]);

        // ---- bitonic merge kd back to descending (32 comparators) ----
        DD(0,8)  DD(1,9)  DD(2,10) DD(3,11) DD(4,12) DD(5,13) DD(6,14) DD(7,15)
        DD(0,4)  DD(1,5)  DD(2,6)  DD(3,7)  DD(8,12) DD(9,13) DD(10,14) DD(11,15)
        DD(0,2)  DD(1,3)  DD(4,6)  DD(5,7)  DD(8,10) DD(9,11) DD(12,14) DD(13,15)
        DD(0,1)  DD(2,3)  DD(4,5)  DD(6,7)  DD(8,9)  DD(10,11) DD(12,13) DD(14,15)
    }
    unsigned* dst = cand + (size_t)rowglob*NCAND + half*64 + quad*16;
    #pragma unroll
    for (int k = 0; k < 4; ++k) {
        int4 w = { (int)kd[4*k+0], (int)kd[4*k+1], (int)kd[4*k+2], (int)kd[4*k+3] };
        *reinterpret_cast<int4*>(dst + 4*k) = w;
    }
}

// ---------------- K2: prefilter (radix-ballot 16th non-self key + margin) -> compact -> exact rerank ----------------
__global__ void k2_refine(const float* __restrict__ x, const float* __restrict__ sq,
                          const unsigned* __restrict__ cand,
                          int* __restrict__ nbr, int* __restrict__ deg)
{
    __shared__ int sb[4][64];
    const int wv   = threadIdx.x >> 6;
    const int w    = blockIdx.x * 4 + wv;                   // point id
    const int lane = threadIdx.x & 63;
    const int b    = w >> 11;
    const int ploc = w & (NPTS-1);
    const int cbase = b * NPTS;
    const float* xc = x + (size_t)cbase * CIN;
    const float* xp = xc + (size_t)ploc * CIN;

    unsigned k0v = cand[(size_t)w * NCAND + lane];
    unsigned k1v = cand[(size_t)w * NCAND + 64 + lane];
    if ((int)(k0v & 0x7FFu) == ploc) k0v = 0xFFFFFFFFu;
    if ((int)(k1v & 0x7FFu) == ploc) k1v = 0xFFFFFFFFu;

    unsigned T = 0xC0000000u;                // biased keys: prefix bits 31..27 = 11000
    #pragma unroll
    for (int bit = 26; bit >= 11; --bit) {
        const unsigned trial = T | (1u << bit);
        const int cnt = __popcll(__ballot(k0v < trial)) + __popcll(__ballot(k1v < trial));
        if (cnt < 16) T = trial;
    }
    const float db16 = fdec(T);
    const unsigned Tk = (fenc(db16 + PREF_MARGIN) & 0xFFFFF800u) | 0x7FFu;  // inclusive

    const bool s0 = (k0v <= Tk), s1 = (k1v <= Tk);
    const unsigned long long lmask = (1ull << lane) - 1ull;
    const unsigned long long m0 = __ballot(s0);
    const int n0 = __popcll(m0);
    if (s0) { int i0 = __popcll(m0 & lmask);       if (i0 < 64) sb[wv][i0] = (int)(k0v & 0x7FFu); }
    const unsigned long long m1 = __ballot(s1);
    if (s1) { int i1 = n0 + __popcll(m1 & lmask);  if (i1 < 64) sb[wv][i1] = (int)(k1v & 0x7FFu); }
    const int n = min(n0 + __popcll(m1), 64);      // n >= 16 structurally; ~20 typically
    __syncthreads();

    float xpl[CIN];
    #pragma unroll
    for (int i = 0; i < CIN/4; ++i) {
        float4 v = *reinterpret_cast<const float4*>(xp + 4*i);
        xpl[4*i+0]=v.x; xpl[4*i+1]=v.y; xpl[4*i+2]=v.z; xpl[4*i+3]=v.w;
    }
    const float sqp = sq[w];

    const int qloc = (lane < n) ? sb[wv][lane] : 0;
    const float* xq = xc + (size_t)qloc * CIN;
    float dot = 0.f;                               // sequential fp32, no FMA (verified recipe)
    #pragma unroll
    for (int i = 0; i < 8; ++i) {
        float4 v0 = *reinterpret_cast<const float4*>(xq + 8*i);
        float4 v1 = *reinterpret_cast<const float4*>(xq + 8*i + 4);
        float g[8] = {v0.x,v0.y,v0.z,v0.w,v1.x,v1.y,v1.z,v1.w};
        #pragma unroll
        for (int u = 0; u < 8; ++u)
            dot = __fadd_rn(dot, __fmul_rn(xpl[8*i+u], g[u]));
    }
    const float sqq = sq[cbase + qloc];
    float d = __fsub_rn(__fadd_rn(sqp, sqq), __fmul_rn(2.f, dot));
    int qcmp = qloc;
    if (lane >= n) { d = INFINITY; qcmp = 0x7fffffff; }

    int rank = 0;
    for (int s = 0; s < n; ++s) {
        const float ds = __shfl(d, s);
        const int   qs = __shfl(qcmp, s);
        rank += (ds < d || (ds == d && qs < qcmp)) ? 1 : 0;
    }
    if (lane < n && rank < KNN) {
        const int ng = cbase + qloc;
        nbr[(size_t)w * KNN + rank] = ng;
        atomicAdd(&deg[ng], 1);
    }
}

// ---------------- K3s: prefix scan (+ zeroes sums, replacing memset) ----------------
__global__ void k3_scan(int* __restrict__ deg, int* __restrict__ rowstart, double* __restrict__ sums)
{
    __shared__ int part[256];
    __shared__ int base[257];
    const int t = threadIdx.x;
    sums[t] = 0.0;                     // 2*COUT = 256 doubles, zeroed before k4's atomics
    int s = 0;
    for (int i = 0; i < 256; ++i) s += deg[t*256 + i];
    part[t] = s;
    __syncthreads();
    if (t == 0) {
        int acc = 0;
        for (int i = 0; i < 256; ++i) { base[i] = acc; acc += part[i]; }
        base[256] = acc;
    }
    __syncthreads();
    int run = base[t];
    for (int i = 0; i < 256; ++i) {
        const int dv = deg[t*256 + i];
        rowstart[t*256 + i] = run;
        deg[t*256 + i] = run;          // deg becomes the write cursor for k3_place
        run += dv;
    }
    if (t == 0) rowstart[NTOT] = base[256];
}

// ---------------- K3a: place edges into reverse lists (counter atomics only) ----------------
__global__ void k3_place(const int* __restrict__ nbr, int* __restrict__ wcur, int* __restrict__ rev)
{
    const int e = blockIdx.x * 256 + threadIdx.x;
    const int c = e >> 4;
    const int n = nbr[e];
    const int pos = atomicAdd(&wcur[n], 1);
    rev[pos] = c;
}

// ---------------- K3g: gather-max, direct broadcast index loads, 8 rows in flight ----------------
__global__ void k3_gather(const float* __restrict__ x, const int* __restrict__ rowstart,
                          const int* __restrict__ rev, float* __restrict__ pooled)
{
    const int n    = blockIdx.x * 4 + (threadIdx.x >> 6);
    const int lane = threadIdx.x & 63;
    const int s = rowstart[n];
    const int e = rowstart[n+1];
    float a0 = -INFINITY, a1 = -INFINITY, a2 = -INFINITY, a3 = -INFINITY;
    int i = s;
    for (; i + 8 <= e; i += 8) {
        const int c0 = rev[i+0], c1 = rev[i+1], c2 = rev[i+2], c3 = rev[i+3];
        const int c4 = rev[i+4], c5 = rev[i+5], c6 = rev[i+6], c7 = rev[i+7];
        const float v0 = x[(size_t)c0 * CIN + lane];
        const float v1 = x[(size_t)c1 * CIN + lane];
        const float v2 = x[(size_t)c2 * CIN + lane];
        const float v3 = x[(size_t)c3 * CIN + lane];
        const float v4 = x[(size_t)c4 * CIN + lane];
        const float v5 = x[(size_t)c5 * CIN + lane];
        const float v6 = x[(size_t)c6 * CIN + lane];
        const float v7 = x[(size_t)c7 * CIN + lane];
        a0 = fmaxf(a0, v0); a1 = fmaxf(a1, v1); a2 = fmaxf(a2, v2); a3 = fmaxf(a3, v3);
        a0 = fmaxf(a0, v4); a1 = fmaxf(a1, v5); a2 = fmaxf(a2, v6); a3 = fmaxf(a3, v7);
    }
    for (; i < e; ++i)
        a0 = fmaxf(a0, x[(size_t)rev[i] * CIN + lane]);
    float acc = fmaxf(fmaxf(a0, a1), fmaxf(a2, a3));
    if (e == s) acc = 0.f;                                  // empty row -> 0 (torch_scatter)
    pooled[(size_t)n * CIN + lane] = acc;
}

// ---------------- K4: y = pooled @ W^T + b, with fused per-channel stats ----------------
__global__ __launch_bounds__(256,2) void k4_linear(const float* __restrict__ pooled, const float* __restrict__ W,
                                                   const float* __restrict__ bias, float* __restrict__ y,
                                                   double* __restrict__ sums)
{
    __shared__ float wl[COUT*68];
    __shared__ float pl[64*68];     // reused post-loop as 2x[16][128] stat partials
    const int t  = threadIdx.x;
    const int r0 = blockIdx.x * 64;
    for (int i = 0; i < (COUT*CIN)/256; ++i) {
        int linear = t + 256*i;
        int c = linear >> 6, k = linear & 63;
        wl[c*68 + k] = W[linear];
    }
    for (int i = 0; i < (64*CIN)/256; ++i) {
        int linear = t + 256*i;
        int r = linear >> 6, k = linear & 63;
        pl[r*68 + k] = pooled[(size_t)(r0 + r)*CIN + k];
    }
    __syncthreads();
    const int tx = t & 15;
    const int ty = t >> 4;
    float acc[4][8];
    #pragma unroll
    for (int j = 0; j < 8; ++j) {
        float bj = bias[tx + 16*j];
        #pragma unroll
        for (int i = 0; i < 4; ++i) acc[i][j] = bj;
    }
    for (int k = 0; k < CIN; k += 4) {
        float4 a[4], bb[8];
        #pragma unroll
        for (int i = 0; i < 4; ++i) a[i]  = *reinterpret_cast<const float4*>(&pl[(ty*4+i)*68 + k]);
        #pragma unroll
        for (int j = 0; j < 8; ++j) bb[j] = *reinterpret_cast<const float4*>(&wl[(tx+16*j)*68 + k]);
        #pragma unroll
        for (int i = 0; i < 4; ++i)
            #pragma unroll
            for (int j = 0; j < 8; ++j) {
                acc[i][j] = fmaf(a[i].x, bb[j].x, acc[i][j]);
                acc[i][j] = fmaf(a[i].y, bb[j].y, acc[i][j]);
                acc[i][j] = fmaf(a[i].z, bb[j].z, acc[i][j]);
                acc[i][j] = fmaf(a[i].w, bb[j].w, acc[i][j]);
            }
    }
    #pragma unroll
    for (int i = 0; i < 4; ++i) {
        float* dst = y + (size_t)(r0 + ty*4 + i) * COUT;
        #pragma unroll
        for (int j = 0; j < 8; ++j) dst[tx + 16*j] = acc[i][j];
    }
    // --- fused stats ---
    __syncthreads();
    #pragma unroll
    for (int j = 0; j < 8; ++j) {
        float s  = ((acc[0][j] + acc[1][j]) + (acc[2][j] + acc[3][j]));
        float ss = ((acc[0][j]*acc[0][j] + acc[1][j]*acc[1][j]) +
                    (acc[2][j]*acc[2][j] + acc[3][j]*acc[3][j]));
        pl[ty*COUT + tx + 16*j]        = s;
        pl[2048 + ty*COUT + tx + 16*j] = ss;
    }
    __syncthreads();
    if (t < COUT) {
        double S = 0.0, SS = 0.0;
        #pragma unroll
        for (int r = 0; r < 16; ++r) {
            S  += (double)pl[r*COUT + t];
            SS += (double)pl[2048 + r*COUT + t];
        }
        atomicAdd(&sums[t], S);
        atomicAdd(&sums[COUT + t], SS);
    }
}

// ---------------- K6: BN scale/shift ----------------
__global__ void k6_bnparam(const double* __restrict__ sums, const float* __restrict__ gamma,
                           const float* __restrict__ beta, float* __restrict__ scsh)
{
    const int t = threadIdx.x;
    const double mean = sums[t] * (1.0/NTOT);
    const double var  = sums[COUT + t] * (1.0/NTOT) - mean*mean;
    const float inv   = (float)rsqrt(var + 1e-5);
    const float sc    = inv * gamma[t];
    scsh[t]        = sc;
    scsh[COUT + t] = beta[t] - (float)mean * sc;
}

// ---------------- K7: out = relu(y*scale + shift) ----------------
__global__ void k7_bnrelu(const float* __restrict__ y, const float* __restrict__ scsh, float* __restrict__ out)
{
    const int g    = blockIdx.x * blockDim.x + threadIdx.x;
    const int base = g * 4;
    float4 v = *reinterpret_cast<const float4*>(y + base);
    const int ch = base & (COUT-1);
    float4 o;
    o.x = fmaxf(0.f, fmaf(v.x, scsh[ch+0], scsh[COUT+ch+0]));
    o.y = fmaxf(0.f, fmaf(v.y, scsh[ch+1], scsh[COUT+ch+1]));
    o.z = fmaxf(0.f, fmaf(v.z, scsh[ch+2], scsh[COUT+ch+2]));
    o.w = fmaxf(0.f, fmaf(v.w, scsh[ch+3], scsh[COUT+ch+3]));
    *reinterpret_cast<float4*>(out + base) = o;
}

extern "C" void kernel_launch(void* const* d_in, const int* in_sizes, int n_in,
                              void* d_out, int out_size, void* d_ws, size_t ws_size,
                              hipStream_t stream)
{
    const float* x     = (const float*)d_in[0];
    const float* W     = (const float*)d_in[2];
    const float* bias  = (const float*)d_in[3];
    const float* gamma = (const float*)d_in[4];
    const float* beta  = (const float*)d_in[5];
    float* out = (float*)d_out;

    // Workspace — explicit 16B-aligned byte offsets (layout as round 12/13):
    //  [0, NTOT*128)          xhi (k0->k1)      }  pooled [0, NTOT*256) (k3g->k4) aliases
    //  [NTOT*256, +NTOT*512)  cand (k1->k2)     }  y (k4->k7) aliases
    //  [NTOT*768, +NTOT*64)   nbr (k2->k3a)
    //  [NTOT*832, +NTOT*4)    deg -> wcur (k0->k2->k3s->k3a)
    //  [.., +(NTOT+4)*4)      rowstart (k3s->k3g)
    //  [.., +NTOT*64)         rev (k3a->k3g)  — ALSO aliased as sqb (k0->k1, dead before k3a)
    //  [.., +NTOT*4)          sq (k0->k2)
    //  [.., +2048)            sums (f64, 16B-aligned)
    //  [.., +1024)            scsh
    char* ws = (char*)d_ws;
    unsigned short* xhi = (unsigned short*)ws;
    float*    pooled   = (float*)ws;
    unsigned* cand     = (unsigned*)(ws + (size_t)NTOT*256);
    float*    y        = (float*)(ws + (size_t)NTOT*256);
    int*      nbr      = (int*)(ws + (size_t)NTOT*768);
    int*      deg      = (int*)(ws + (size_t)NTOT*832);            // becomes wcur after k3_scan
    int*      rowstart = (int*)(ws + (size_t)NTOT*836);
    int*      rev      = (int*)(ws + (size_t)NTOT*840 + 16);
    float*    sqb      = (float*)rev;                              // aliased: k0->k1 only
    float*    sq       = (float*)(ws + (size_t)NTOT*904 + 16);
    double*   sums     = (double*)(ws + (size_t)NTOT*908 + 16);    // 16B aligned
    float*    scsh     = (float*)(ws + (size_t)NTOT*908 + 16 + 2048);

    k0_prep  <<<NTOT/256,   256, 0, stream>>>(x, xhi, sq, sqb, deg);
    k1_knn   <<<NTOT/32,    256, 0, stream>>>(xhi, sqb, cand);   // 2048 blocks
    k2_refine<<<NTOT/4,     256, 0, stream>>>(x, sq, cand, nbr, deg);

    k3_scan  <<<1,          256, 0, stream>>>(deg, rowstart, sums);
    k3_place <<<NTOT*KNN/256,256,0, stream>>>(nbr, deg, rev);
    k3_gather<<<NTOT/4,     256, 0, stream>>>(x, rowstart, rev, pooled);

    k4_linear <<<NTOT/64, 256, 0, stream>>>(pooled, W, bias, y, sums);
    k6_bnparam<<<1,      COUT, 0, stream>>>(sums, gamma, beta, scsh);
    k7_bnrelu <<<(NTOT*COUT/4)/256, 256, 0, stream>>>(y, scsh, out);
}

// Round 15
// 403.233 us; speedup vs baseline: 2.2223x; 1.1767x over previous
//
#include <hip/hip_runtime.h>
#include <hip/hip_bf16.h>
#include <math.h>

#define NPTS 2048
#define NCLOUD 32
#define NTOT (NPTS*NCLOUD)
#define CIN 64
#define COUT 128
#define KNN 16
#define NCAND 128          // 8 subsets (2 col-halves x 4 quads) * 16
#define PREF_MARGIN 0.6f   // prefilter margin (approx-key err ~0.3 + key quant)

typedef __attribute__((ext_vector_type(8))) short short8v;   // 8 bf16 (4 VGPR)
typedef __attribute__((ext_vector_type(4))) float float4v;   // 4 fp32

__device__ __forceinline__ unsigned short f2bf(float f) {    // RNE float->bf16
    unsigned u = __float_as_uint(f);
    return (unsigned short)((u + 0x7fffu + ((u >> 16) & 1u)) >> 16);
}
__device__ __forceinline__ unsigned fenc(float f) {          // monotone float->uint
    unsigned u = __float_as_uint(f);
    return u ^ (unsigned)(((int)u >> 31) | 0x80000000);
}
__device__ __forceinline__ float fdec(unsigned u) {          // inverse of fenc
    unsigned m = (unsigned)(((int)(~u) >> 31)) | 0x80000000u;
    return __uint_as_float(u ^ m);
}

// np.sum pairwise-8 replication for 64 squares (fp32, no FMA) — BIT-IDENTICAL recipe.
__device__ __forceinline__ float np_sq64(const float* __restrict__ v)
{
    float r[8];
    #pragma unroll
    for (int j = 0; j < 8; ++j) r[j] = __fmul_rn(v[j], v[j]);
    #pragma unroll
    for (int i = 1; i < 8; ++i)
        #pragma unroll
        for (int j = 0; j < 8; ++j) r[j] = __fadd_rn(r[j], __fmul_rn(v[8*i+j], v[8*i+j]));
    return __fadd_rn(__fadd_rn(__fadd_rn(r[0],r[1]), __fadd_rn(r[2],r[3])),
                     __fadd_rn(__fadd_rn(r[4],r[5]), __fadd_rn(r[6],r[7])));
}

// ---------------- K0: bf16 row plane (B-operand) + MFMA-fragment-tiled plane (A-operand)
//                  + np-faithful |q|^2 (+biased) + deg zero ----------------
// xat layout: per 16-point tile T, 2KB block; lane l(=quad*16+j) fragment for K-half h at
//   xat_shorts[T*1024 + h*512 + l*8] = point (T*16+j), dims (quad*8 + h*32)..+8
// -> k1's A-loads are contiguous 1KB per wave (ideal coalescing; removes the 16-segment
//    scattered pattern that was saturating the L1 request path at ~170us).
__global__ void k0_prep(const float* __restrict__ x, unsigned short* __restrict__ xhi,
                        unsigned short* __restrict__ xat,
                        float* __restrict__ sq, float* __restrict__ sqb, int* __restrict__ deg)
{
    const int p = blockIdx.x * 256 + threadIdx.x;
    const int tile = p >> 4, j = p & 15;
    const float* src = x + (size_t)p * CIN;
    float e[CIN];
    #pragma unroll
    for (int i = 0; i < 8; ++i) {                  // i: 8-dim group; quad=i&3, h=i>>2
        float4 v0 = *reinterpret_cast<const float4*>(src + 8*i);
        float4 v1 = *reinterpret_cast<const float4*>(src + 8*i + 4);
        e[8*i+0]=v0.x; e[8*i+1]=v0.y; e[8*i+2]=v0.z; e[8*i+3]=v0.w;
        e[8*i+4]=v1.x; e[8*i+5]=v1.y; e[8*i+6]=v1.z; e[8*i+7]=v1.w;
        short8v h;
        #pragma unroll
        for (int u = 0; u < 8; ++u) h[u] = (short)f2bf(e[8*i+u]);
        *reinterpret_cast<short8v*>(xhi + (size_t)p*CIN + 8*i) = h;
        *reinterpret_cast<short8v*>(xat + (size_t)tile*1024 + (i>>2)*512 + ((i&3)*16 + j)*8) = h;
    }
    const float s = np_sq64(e);
    sq[p]  = s;           // exact (k2)
    sqb[p] = s + 16.f;    // biased (k1 keys; always > 0)
    deg[p] = 0;           // replaces memset
}

// Comparators: KA = ascending on key[], DD = descending on kd[].
#define KA(a,b) { const unsigned _x = key[a], _y = key[b]; key[a] = min(_x,_y); key[b] = max(_x,_y); }
#define DD(a,b) { const unsigned _x = kd[a],  _y = kd[b];  kd[a]  = max(_x,_y); kd[b]  = min(_x,_y); }

// ---------------- K1: MFMA swapped-operand KNN + Batcher-63 top-16, coalesced A-loads ----------------
__global__ __launch_bounds__(256,1) void k1_knn(const unsigned short* __restrict__ xhi,
                                                const unsigned short* __restrict__ xat,
                                                const float* __restrict__ sqb,
                                                unsigned* __restrict__ cand)
{
    const int wid  = ((blockIdx.x & 7) << 8) + (blockIdx.x >> 3);  // XCD swizzle (4 clouds/XCD)
    const int o    = wid >> 1;           // row group (64 rows)
    const int half = wid & 1;            // column half
    const int wave = threadIdx.x >> 6;
    const int lane = threadIdx.x & 63;
    const int j    = lane & 15;
    const int quad = lane >> 4;
    const int rowglob = o*64 + wave*16 + j;
    const int cloud   = rowglob >> 11;
    const int cbase   = cloud << 11;               // cloud base point id

    // B-operand (row vectors) from row-major plane
    const short8v bhi0 = *reinterpret_cast<const short8v*>(xhi + (size_t)rowglob*CIN + quad*8);
    const short8v bhi1 = *reinterpret_cast<const short8v*>(xhi + (size_t)rowglob*CIN + quad*8 + 32);

    unsigned kd[16];                   // DESC: kd[0] = worst kept
    #pragma unroll
    for (int k = 0; k < 16; ++k) kd[k] = 0xFFFFFFFFu;

    // A-operand: fragment-tiled plane; per tile, lane's 16B at tile*1024 + h*512 + lane*8 (shorts)
    const unsigned short* pt0 = xat + (size_t)(cloud*128 + half*64)*1024 + lane*8;
    const float*          ps0 = sqb + cbase + half*1024 + quad*4;

    // prefetch sub0 of batch 0
    short8v pfa0 = *reinterpret_cast<const short8v*>(pt0);
    short8v pfa1 = *reinterpret_cast<const short8v*>(pt0 + 512);

    for (int it4 = 0; it4 < 16; ++it4) {           // 16 batches x 4 tiles x 16 cols
        unsigned key[16];
        const unsigned idb = (unsigned)(half*1024 + it4*64 + quad*4) | 0x80000000u;

        // ---- sub 0 (from prefetch regs) ----
        {
            float4v acc0 = {0.f,0.f,0.f,0.f}, acc1 = {0.f,0.f,0.f,0.f};
            acc0 = __builtin_amdgcn_mfma_f32_16x16x32_bf16(pfa0, bhi0, acc0, 0,0,0);
            acc1 = __builtin_amdgcn_mfma_f32_16x16x32_bf16(pfa1, bhi1, acc1, 0,0,0);
            const float4v sqv = *reinterpret_cast<const float4v*>(ps0 + it4*64);
            #pragma unroll
            for (int r = 0; r < 4; ++r) {
                const float s = fmaf(-2.f, acc0[r] + acc1[r], sqv[r]);
                key[r] = (__float_as_uint(s) & 0xFFFFF800u) | (idb + (unsigned)r);
            }
        }
        // ---- prefetch sub0 of next batch ----
        {
            const int nxt = (it4 < 15) ? it4 + 1 : 15;
            const unsigned short* pan = pt0 + (size_t)(nxt*4)*1024;
            pfa0 = *reinterpret_cast<const short8v*>(pan);
            pfa1 = *reinterpret_cast<const short8v*>(pan + 512);
        }
        // ---- subs 1..3 inline (each: two contiguous 1KB wave-loads) ----
        #pragma unroll
        for (int sub = 1; sub < 4; ++sub) {
            const unsigned short* pa = pt0 + (size_t)(it4*4 + sub)*1024;
            const short8v a0 = *reinterpret_cast<const short8v*>(pa);
            const short8v a1 = *reinterpret_cast<const short8v*>(pa + 512);
            float4v acc0 = {0.f,0.f,0.f,0.f}, acc1 = {0.f,0.f,0.f,0.f};
            acc0 = __builtin_amdgcn_mfma_f32_16x16x32_bf16(a0, bhi0, acc0, 0,0,0);
            acc1 = __builtin_amdgcn_mfma_f32_16x16x32_bf16(a1, bhi1, acc1, 0,0,0);
            const float4v sqv = *reinterpret_cast<const float4v*>(ps0 + it4*64 + sub*16);
            #pragma unroll
            for (int r = 0; r < 4; ++r) {
                const float s = fmaf(-2.f, acc0[r] + acc1[r], sqv[r]);
                key[sub*4 + r] = (__float_as_uint(s) & 0xFFFFF800u) | (idb + (unsigned)(sub*16 + r));
            }
        }

        // ---- Batcher odd-even mergesort-16 ascending (63 comparators) ----
        KA(0,1) KA(2,3) KA(4,5) KA(6,7)
        KA(0,2) KA(1,3) KA(4,6) KA(5,7)
        KA(1,2) KA(5,6)
        KA(0,4) KA(1,5) KA(2,6) KA(3,7)
        KA(2,4) KA(3,5)
        KA(1,2) KA(3,4) KA(5,6)
        KA(8,9) KA(10,11) KA(12,13) KA(14,15)
        KA(8,10) KA(9,11) KA(12,14) KA(13,15)
        KA(9,10) KA(13,14)
        KA(8,12) KA(9,13) KA(10,14) KA(11,15)
        KA(10,12) KA(11,13)
        KA(9,10) KA(11,12) KA(13,14)
        KA(0,8) KA(1,9) KA(2,10) KA(3,11) KA(4,12) KA(5,13) KA(6,14) KA(7,15)
        KA(4,8) KA(5,9) KA(6,10) KA(7,11)
        KA(2,4) KA(3,5) KA(6,8) KA(7,9) KA(10,12) KA(11,13)
        KA(1,2) KA(3,4) KA(5,6) KA(7,8) KA(9,10) KA(11,12) KA(13,14)

        // ---- half-clean: [kd desc | key asc] -> kd = bottom-16 (bitonic) ----
        #pragma unroll
        for (int i = 0; i < 16; ++i) kd[i] = min(kd[i], key[i]);

        // ---- bitonic merge kd back to descending (32 comparators) ----
        DD(0,8)  DD(1,9)  DD(2,10) DD(3,11) DD(4,12) DD(5,13) DD(6,14) DD(7,15)
        DD(0,4)  DD(1,5)  DD(2,6)  DD(3,7)  DD(8,12) DD(9,13) DD(10,14) DD(11,15)
        DD(0,2)  DD(1,3)  DD(4,6)  DD(5,7)  DD(8,10) DD(9,11) DD(12,14) DD(13,15)
        DD(0,1)  DD(2,3)  DD(4,5)  DD(6,7)  DD(8,9)  DD(10,11) DD(12,13) DD(14,15)
    }
    unsigned* dst = cand + (size_t)rowglob*NCAND + half*64 + quad*16;
    #pragma unroll
    for (int k = 0; k < 4; ++k) {
        int4 w = { (int)kd[4*k+0], (int)kd[4*k+1], (int)kd[4*k+2], (int)kd[4*k+3] };
        *reinterpret_cast<int4*>(dst + 4*k) = w;
    }
}

// ---------------- K2: prefilter (radix-ballot 16th non-self key + margin) -> compact -> exact rerank ----------------
__global__ void k2_refine(const float* __restrict__ x, const float* __restrict__ sq,
                          const unsigned* __restrict__ cand,
                          int* __restrict__ nbr, int* __restrict__ deg)
{
    __shared__ int sb[4][64];
    const int wv   = threadIdx.x >> 6;
    const int w    = blockIdx.x * 4 + wv;                   // point id
    const int lane = threadIdx.x & 63;
    const int b    = w >> 11;
    const int ploc = w & (NPTS-1);
    const int cbase = b * NPTS;
    const float* xc = x + (size_t)cbase * CIN;
    const float* xp = xc + (size_t)ploc * CIN;

    unsigned k0v = cand[(size_t)w * NCAND + lane];
    unsigned k1v = cand[(size_t)w * NCAND + 64 + lane];
    if ((int)(k0v & 0x7FFu) == ploc) k0v = 0xFFFFFFFFu;
    if ((int)(k1v & 0x7FFu) == ploc) k1v = 0xFFFFFFFFu;

    unsigned T = 0xC0000000u;                // biased keys: prefix bits 31..27 = 11000
    #pragma unroll
    for (int bit = 26; bit >= 11; --bit) {
        const unsigned trial = T | (1u << bit);
        const int cnt = __popcll(__ballot(k0v < trial)) + __popcll(__ballot(k1v < trial));
        if (cnt < 16) T = trial;
    }
    const float db16 = fdec(T);
    const unsigned Tk = (fenc(db16 + PREF_MARGIN) & 0xFFFFF800u) | 0x7FFu;  // inclusive

    const bool s0 = (k0v <= Tk), s1 = (k1v <= Tk);
    const unsigned long long lmask = (1ull << lane) - 1ull;
    const unsigned long long m0 = __ballot(s0);
    const int n0 = __popcll(m0);
    if (s0) { int i0 = __popcll(m0 & lmask);       if (i0 < 64) sb[wv][i0] = (int)(k0v & 0x7FFu); }
    const unsigned long long m1 = __ballot(s1);
    if (s1) { int i1 = n0 + __popcll(m1 & lmask);  if (i1 < 64) sb[wv][i1] = (int)(k1v & 0x7FFu); }
    const int n = min(n0 + __popcll(m1), 64);      // n >= 16 structurally; ~20 typically
    __syncthreads();

    float xpl[CIN];
    #pragma unroll
    for (int i = 0; i < CIN/4; ++i) {
        float4 v = *reinterpret_cast<const float4*>(xp + 4*i);
        xpl[4*i+0]=v.x; xpl[4*i+1]=v.y; xpl[4*i+2]=v.z; xpl[4*i+3]=v.w;
    }
    const float sqp = sq[w];

    const int qloc = (lane < n) ? sb[wv][lane] : 0;
    const float* xq = xc + (size_t)qloc * CIN;
    float dot = 0.f;                               // sequential fp32, no FMA (verified recipe)
    #pragma unroll
    for (int i = 0; i < 8; ++i) {
        float4 v0 = *reinterpret_cast<const float4*>(xq + 8*i);
        float4 v1 = *reinterpret_cast<const float4*>(xq + 8*i + 4);
        float g[8] = {v0.x,v0.y,v0.z,v0.w,v1.x,v1.y,v1.z,v1.w};
        #pragma unroll
        for (int u = 0; u < 8; ++u)
            dot = __fadd_rn(dot, __fmul_rn(xpl[8*i+u], g[u]));
    }
    const float sqq = sq[cbase + qloc];
    float d = __fsub_rn(__fadd_rn(sqp, sqq), __fmul_rn(2.f, dot));
    int qcmp = qloc;
    if (lane >= n) { d = INFINITY; qcmp = 0x7fffffff; }

    int rank = 0;
    for (int s = 0; s < n; ++s) {
        const float ds = __shfl(d, s);
        const int   qs = __shfl(qcmp, s);
        rank += (ds < d || (ds == d && qs < qcmp)) ? 1 : 0;
    }
    if (lane < n && rank < KNN) {
        const int ng = cbase + qloc;
        nbr[(size_t)w * KNN + rank] = ng;
        atomicAdd(&deg[ng], 1);
    }
}

// ---------------- K3s: prefix scan (+ zeroes sums, replacing memset) ----------------
__global__ void k3_scan(int* __restrict__ deg, int* __restrict__ rowstart, double* __restrict__ sums)
{
    __shared__ int part[256];
    __shared__ int base[257];
    const int t = threadIdx.x;
    sums[t] = 0.0;
    int s = 0;
    for (int i = 0; i < 256; ++i) s += deg[t*256 + i];
    part[t] = s;
    __syncthreads();
    if (t == 0) {
        int acc = 0;
        for (int i = 0; i < 256; ++i) { base[i] = acc; acc += part[i]; }
        base[256] = acc;
    }
    __syncthreads();
    int run = base[t];
    for (int i = 0; i < 256; ++i) {
        const int dv = deg[t*256 + i];
        rowstart[t*256 + i] = run;
        deg[t*256 + i] = run;          // deg becomes the write cursor for k3_place
        run += dv;
    }
    if (t == 0) rowstart[NTOT] = base[256];
}

// ---------------- K3a: place edges into reverse lists (counter atomics only) ----------------
__global__ void k3_place(const int* __restrict__ nbr, int* __restrict__ wcur, int* __restrict__ rev)
{
    const int e = blockIdx.x * 256 + threadIdx.x;
    const int c = e >> 4;
    const int n = nbr[e];
    const int pos = atomicAdd(&wcur[n], 1);
    rev[pos] = c;
}

// ---------------- K3g: gather-max, direct broadcast index loads, 8 rows in flight ----------------
__global__ void k3_gather(const float* __restrict__ x, const int* __restrict__ rowstart,
                          const int* __restrict__ rev, float* __restrict__ pooled)
{
    const int n    = blockIdx.x * 4 + (threadIdx.x >> 6);
    const int lane = threadIdx.x & 63;
    const int s = rowstart[n];
    const int e = rowstart[n+1];
    float a0 = -INFINITY, a1 = -INFINITY, a2 = -INFINITY, a3 = -INFINITY;
    int i = s;
    for (; i + 8 <= e; i += 8) {
        const int c0 = rev[i+0], c1 = rev[i+1], c2 = rev[i+2], c3 = rev[i+3];
        const int c4 = rev[i+4], c5 = rev[i+5], c6 = rev[i+6], c7 = rev[i+7];
        const float v0 = x[(size_t)c0 * CIN + lane];
        const float v1 = x[(size_t)c1 * CIN + lane];
        const float v2 = x[(size_t)c2 * CIN + lane];
        const float v3 = x[(size_t)c3 * CIN + lane];
        const float v4 = x[(size_t)c4 * CIN + lane];
        const float v5 = x[(size_t)c5 * CIN + lane];
        const float v6 = x[(size_t)c6 * CIN + lane];
        const float v7 = x[(size_t)c7 * CIN + lane];
        a0 = fmaxf(a0, v0); a1 = fmaxf(a1, v1); a2 = fmaxf(a2, v2); a3 = fmaxf(a3, v3);
        a0 = fmaxf(a0, v4); a1 = fmaxf(a1, v5); a2 = fmaxf(a2, v6); a3 = fmaxf(a3, v7);
    }
    for (; i < e; ++i)
        a0 = fmaxf(a0, x[(size_t)rev[i] * CIN + lane]);
    float acc = fmaxf(fmaxf(a0, a1), fmaxf(a2, a3));
    if (e == s) acc = 0.f;                                  // empty row -> 0 (torch_scatter)
    pooled[(size_t)n * CIN + lane] = acc;
}

// ---------------- K4: y = pooled @ W^T + b, with fused per-channel stats ----------------
__global__ __launch_bounds__(256,2) void k4_linear(const float* __restrict__ pooled, const float* __restrict__ W,
                                                   const float* __restrict__ bias, float* __restrict__ y,
                                                   double* __restrict__ sums)
{
    __shared__ float wl[COUT*68];
    __shared__ float pl[64*68];     // reused post-loop as 2x[16][128] stat partials
    const int t  = threadIdx.x;
    const int r0 = blockIdx.x * 64;
    for (int i = 0; i < (COUT*CIN)/256; ++i) {
        int linear = t + 256*i;
        int c = linear >> 6, k = linear & 63;
        wl[c*68 + k] = W[linear];
    }
    for (int i = 0; i < (64*CIN)/256; ++i) {
        int linear = t + 256*i;
        int r = linear >> 6, k = linear & 63;
        pl[r*68 + k] = pooled[(size_t)(r0 + r)*CIN + k];
    }
    __syncthreads();
    const int tx = t & 15;
    const int ty = t >> 4;
    float acc[4][8];
    #pragma unroll
    for (int j = 0; j < 8; ++j) {
        float bj = bias[tx + 16*j];
        #pragma unroll
        for (int i = 0; i < 4; ++i) acc[i][j] = bj;
    }
    for (int k = 0; k < CIN; k += 4) {
        float4 a[4], bb[8];
        #pragma unroll
        for (int i = 0; i < 4; ++i) a[i]  = *reinterpret_cast<const float4*>(&pl[(ty*4+i)*68 + k]);
        #pragma unroll
        for (int j = 0; j < 8; ++j) bb[j] = *reinterpret_cast<const float4*>(&wl[(tx+16*j)*68 + k]);
        #pragma unroll
        for (int i = 0; i < 4; ++i)
            #pragma unroll
            for (int j = 0; j < 8; ++j) {
                acc[i][j] = fmaf(a[i].x, bb[j].x, acc[i][j]);
                acc[i][j] = fmaf(a[i].y, bb[j].y, acc[i][j]);
                acc[i][j] = fmaf(a[i].z, bb[j].z, acc[i][j]);
                acc[i][j] = fmaf(a[i].w, bb[j].w, acc[i][j]);
            }
    }
    #pragma unroll
    for (int i = 0; i < 4; ++i) {
        float* dst = y + (size_t)(r0 + ty*4 + i) * COUT;
        #pragma unroll
        for (int j = 0; j < 8; ++j) dst[tx + 16*j] = acc[i][j];
    }
    // --- fused stats ---
    __syncthreads();
    #pragma unroll
    for (int j = 0; j < 8; ++j) {
        float s  = ((acc[0][j] + acc[1][j]) + (acc[2][j] + acc[3][j]));
        float ss = ((acc[0][j]*acc[0][j] + acc[1][j]*acc[1][j]) +
                    (acc[2][j]*acc[2][j] + acc[3][j]*acc[3][j]));
        pl[ty*COUT + tx + 16*j]        = s;
        pl[2048 + ty*COUT + tx + 16*j] = ss;
    }
    __syncthreads();
    if (t < COUT) {
        double S = 0.0, SS = 0.0;
        #pragma unroll
        for (int r = 0; r < 16; ++r) {
            S  += (double)pl[r*COUT + t];
            SS += (double)pl[2048 + r*COUT + t];
        }
        atomicAdd(&sums[t], S);
        atomicAdd(&sums[COUT + t], SS);
    }
}

// ---------------- K6: BN scale/shift ----------------
__global__ void k6_bnparam(const double* __restrict__ sums, const float* __restrict__ gamma,
                           const float* __restrict__ beta, float* __restrict__ scsh)
{
    const int t = threadIdx.x;
    const double mean = sums[t] * (1.0/NTOT);
    const double var  = sums[COUT + t] * (1.0/NTOT) - mean*mean;
    const float inv   = (float)rsqrt(var + 1e-5);
    const float sc    = inv * gamma[t];
    scsh[t]        = sc;
    scsh[COUT + t] = beta[t] - (float)mean * sc;
}

// ---------------- K7: out = relu(y*scale + shift) ----------------
__global__ void k7_bnrelu(const float* __restrict__ y, const float* __restrict__ scsh, float* __restrict__ out)
{
    const int g    = blockIdx.x * blockDim.x + threadIdx.x;
    const int base = g * 4;
    float4 v = *reinterpret_cast<const float4*>(y + base);
    const int ch = base & (COUT-1);
    float4 o;
    o.x = fmaxf(0.f, fmaf(v.x, scsh[ch+0], scsh[COUT+ch+0]));
    o.y = fmaxf(0.f, fmaf(v.y, scsh[ch+1], scsh[COUT+ch+1]));
    o.z = fmaxf(0.f, fmaf(v.z, scsh[ch+2], scsh[COUT+ch+2]));
    o.w = fmaxf(0.f, fmaf(v.w, scsh[ch+3], scsh[COUT+ch+3]));
    *reinterpret_cast<float4*>(out + base) = o;
}

extern "C" void kernel_launch(void* const* d_in, const int* in_sizes, int n_in,
                              void* d_out, int out_size, void* d_ws, size_t ws_size,
                              hipStream_t stream)
{
    const float* x     = (const float*)d_in[0];
    const float* W     = (const float*)d_in[2];
    const float* bias  = (const float*)d_in[3];
    const float* gamma = (const float*)d_in[4];
    const float* beta  = (const float*)d_in[5];
    float* out = (float*)d_out;

    // Workspace — explicit 16B-aligned byte offsets:
    //  [0, NTOT*128)          xhi  (k0->k1 B-plane)   } pooled [0, NTOT*256) (k3g->k4) aliases
    //  [NTOT*128, +NTOT*128)  xat  (k0->k1 A-plane)   }
    //  [NTOT*256, +NTOT*512)  cand (k1->k2)           } y (k4->k7) aliases
    //  [NTOT*768, +NTOT*64)   nbr (k2->k3a)
    //  [NTOT*832, +NTOT*4)    deg -> wcur
    //  [.., +(NTOT+4)*4)      rowstart
    //  [.., +NTOT*64)         rev — ALSO aliased as sqb (k0->k1, dead before k3a)
    //  [.., +NTOT*4)          sq
    //  [.., +2048)            sums (f64, 16B-aligned)
    //  [.., +1024)            scsh
    char* ws = (char*)d_ws;
    unsigned short* xhi = (unsigned short*)ws;
    unsigned short* xat = (unsigned short*)(ws + (size_t)NTOT*128);
    float*    pooled   = (float*)ws;
    unsigned* cand     = (unsigned*)(ws + (size_t)NTOT*256);
    float*    y        = (float*)(ws + (size_t)NTOT*256);
    int*      nbr      = (int*)(ws + (size_t)NTOT*768);
    int*      deg      = (int*)(ws + (size_t)NTOT*832);            // becomes wcur after k3_scan
    int*      rowstart = (int*)(ws + (size_t)NTOT*836);
    int*      rev      = (int*)(ws + (size_t)NTOT*840 + 16);
    float*    sqb      = (float*)rev;                              // aliased: k0->k1 only
    float*    sq       = (float*)(ws + (size_t)NTOT*904 + 16);
    double*   sums     = (double*)(ws + (size_t)NTOT*908 + 16);    // 16B aligned
    float*    scsh     = (float*)(ws + (size_t)NTOT*908 + 16 + 2048);

    k0_prep  <<<NTOT/256,   256, 0, stream>>>(x, xhi, xat, sq, sqb, deg);
    k1_knn   <<<NTOT/32,    256, 0, stream>>>(xhi, xat, sqb, cand);   // 2048 blocks
    k2_refine<<<NTOT/4,     256, 0, stream>>>(x, sq, cand, nbr, deg);

    k3_scan  <<<1,          256, 0, stream>>>(deg, rowstart, sums);
    k3_place <<<NTOT*KNN/256,256,0, stream>>>(nbr, deg, rev);
    k3_gather<<<NTOT/4,     256, 0, stream>>>(x, rowstart, rev, pooled);

    k4_linear <<<NTOT/64, 256, 0, stream>>>(pooled, W, bias, y, sums);
    k6_bnparam<<<1,      COUT, 0, stream>>>(sums, gamma, beta, scsh);
    k7_bnrelu <<<(NTOT*COUT/4)/256, 256, 0, stream>>>(y, scsh, out);
}